// Round 15
// baseline (469.376 us; speedup 1.0000x reference)
//
#include <hip/hip_runtime.h>
#include <hip/hip_fp16.h>

typedef _Float16 f16;
typedef _Float16 f16x8 __attribute__((ext_vector_type(8)));
typedef _Float16 f16x4 __attribute__((ext_vector_type(4)));
typedef float f32x4 __attribute__((ext_vector_type(4)));

static constexpr int BB = 8, HH = 224, WW = 224, NP = HH * WW; // 50176
static constexpr int TOPK = 15052;  // max(int(0.3*224*224), 64)
static constexpr int LDR = 72;      // LDS row stride (f16)
static constexpr int CHUNKS = NP / 256;  // 196
static constexpr int HB = 28;       // hist blocks per batch; NP/HB = 1792

// XOR-swizzled LDS index for buf (fixes px8-strided scalar-write 16-way conflict).
__device__ __forceinline__ int BIDX(int px, int ci) {
  return px * LDR + (ci ^ (((px >> 3) & 7) << 3));
}

// ---------------- K2 (fused): m = sigmoid(conv3x3(relu(A_j x + B_j)) + b)
__global__ __launch_bounds__(256) void k_m(const float* __restrict__ x,
    const float* __restrict__ w_in, const float* __restrict__ b_in,
    const float* __restrict__ imp1_w, const float* __restrict__ imp1_b,
    const float* __restrict__ imp2_w, const float* __restrict__ imp2_b,
    float* __restrict__ m) {
  __shared__ float A[16], Bv[16], w2[144];
  __shared__ float bsh;
  int t = threadIdx.x;
  if (t < 144) w2[t] = imp2_w[t];
  if (t == 0) bsh = imp2_b[0];
  if (t < 16) {
    float a = 0.f, bb = 0.f;
    for (int c = 0; c < 64; c++) {
      float iw = imp1_w[t * 64 + c];
      a = fmaf(iw, w_in[64 + c], a);
      bb = fmaf(iw, b_in[64 + c], bb);
    }
    A[t] = a;
    Bv[t] = bb + imp1_b[t];
  }
  __syncthreads();
  int p = blockIdx.x * 256 + t;
  int b = p / NP, pp = p - b * NP;
  int h = pp / WW, w = pp - h * WW;
  const float* xb = x + (size_t)b * NP;
  float s = bsh;
#pragma unroll
  for (int ky = 0; ky < 3; ky++) {
    int hy = h + ky - 1;
    if ((unsigned)hy >= (unsigned)HH) continue;
#pragma unroll
    for (int kx = 0; kx < 3; kx++) {
      int wx = w + kx - 1;
      if ((unsigned)wx >= (unsigned)WW) continue;
      float xn = xb[hy * WW + wx];
#pragma unroll
      for (int j = 0; j < 16; j++) {
        float m1 = fmaxf(fmaf(A[j], xn, Bv[j]), 0.f);
        s = fmaf(w2[j * 9 + ky * 3 + kx], m1, s);
      }
    }
  }
  m[p] = 1.f / (1.f + expf(-s));
}

// ---------------- K_setup: block-invariant epilogue constants
__global__ __launch_bounds__(64) void k_setup(const float* __restrict__ w_in,
    const float* __restrict__ b_in, const float* __restrict__ out_b,
    const float* __restrict__ fc_w, const float* __restrict__ fc_b,
    float* __restrict__ fcA, float* __restrict__ bDg) {
  int d = threadIdx.x;
  float fa = 0.f, fb = 0.f;
  for (int c = 0; c < 64; c++) {
    float fw = fc_w[d * 64 + c];
    fa = fmaf(fw, w_in[c], fa);
    fb = fmaf(fw, b_in[c], fb);
  }
  fcA[d] = fa;
  bDg[d] = out_b[d] + fc_b[d] + fb;
}

// ---------------- K3a: init select state
__global__ __launch_bounds__(256) void k_init(unsigned* __restrict__ ghist,
    unsigned* __restrict__ prefix, int* __restrict__ rem) {
  int i = blockIdx.x * 256 + threadIdx.x;
  if (i < 8 * 2048) ghist[i] = 0u;
  if (i < 8) { prefix[i] = 0u; rem[i] = TOPK; }
}

// ---------------- K3b: grid-parallel histogram of one radix digit
template <int SHIFT, unsigned HIMASK, int BINS>
__global__ __launch_bounds__(256) void k_hist(const float* __restrict__ m,
    const unsigned* __restrict__ prefix, unsigned* __restrict__ ghist) {
  __shared__ unsigned hist[2048];
  int b = blockIdx.y, blk = blockIdx.x, t = threadIdx.x;
  for (int i = t; i < BINS; i += 256) hist[i] = 0u;
  __syncthreads();
  unsigned pfx = prefix[b];
  const float* mb = m + (size_t)b * NP + blk * (NP / HB);
#pragma unroll
  for (int it = 0; it < NP / HB / 256; it++) {
    unsigned bits = __float_as_uint(mb[it * 256 + t]);
    if ((bits & HIMASK) == pfx) atomicAdd(&hist[(bits >> SHIFT) & (BINS - 1)], 1u);
  }
  __syncthreads();
  unsigned* gh = ghist + b * 2048;
  for (int i = t; i < BINS; i += 256) {
    unsigned v = hist[i];
    if (v) atomicAdd(&gh[i], v);
  }
}

// ---------------- K3c: pick k-th bin via suffix scan; advance prefix/rem; zero ghist
template <int SHIFT, int BINS, int FINAL>
__global__ __launch_bounds__(256) void k_pick(unsigned* __restrict__ ghist,
    unsigned* __restrict__ prefix, int* __restrict__ rem,
    unsigned* __restrict__ selT, int* __restrict__ selNeed) {
  __shared__ unsigned s[256];
  int b = blockIdx.x, t = threadIdx.x;
  constexpr int PER = BINS / 256;
  unsigned* gh = ghist + b * 2048;
  unsigned local[PER];
  unsigned sum = 0;
#pragma unroll
  for (int j = 0; j < PER; j++) { local[j] = gh[t * PER + j]; sum += local[j]; }
#pragma unroll
  for (int j = 0; j < PER; j++) gh[t * PER + j] = 0u;
  s[t] = sum;
  int rm = rem[b];
  unsigned pfx = prefix[b];
  __syncthreads();
  for (int o = 1; o < 256; o <<= 1) {
    unsigned v = (t + o < 256) ? s[t + o] : 0u;
    __syncthreads();
    s[t] += v;
    __syncthreads();
  }
  unsigned nb = (t < 255) ? s[t + 1] : 0u;
  if (s[t] >= (unsigned)rm && nb < (unsigned)rm) {
    int acc = (int)nb;
#pragma unroll
    for (int j = PER - 1; j >= 0; j--) {
      acc += (int)local[j];
      if (acc >= rm) {
        unsigned bin = (unsigned)(t * PER + j);
        int need = rm - (acc - (int)local[j]);
        if (FINAL) {
          selT[b] = pfx | (bin << SHIFT);
          selNeed[b] = need;
        } else {
          prefix[b] = pfx | (bin << SHIFT);
          rem[b] = need;
        }
        break;
      }
    }
  }
}

// ---------------- K4a: per-chunk count of (bits == T)
__global__ __launch_bounds__(256) void k_cnteq(const float* __restrict__ m,
    const unsigned* __restrict__ selT, unsigned* __restrict__ cnt) {
  int b = blockIdx.y, ch = blockIdx.x, t = threadIdx.x;
  unsigned T = selT[b];
  unsigned bits = __float_as_uint(m[(size_t)b * NP + ch * 256 + t]);
  unsigned long long em = __ballot(bits == T);
  __shared__ unsigned wc[4];
  if ((t & 63) == 0) wc[t >> 6] = (unsigned)__popcll(em);
  __syncthreads();
  if (t == 0) cnt[b * CHUNKS + ch] = wc[0] + wc[1] + wc[2] + wc[3];
}

// ---------------- K4b: per-batch exclusive scan of chunk counts
__global__ __launch_bounds__(256) void k_scan(unsigned* __restrict__ cnt) {
  __shared__ unsigned s[256];
  int b = blockIdx.x, t = threadIdx.x;
  unsigned v = (t < CHUNKS) ? cnt[b * CHUNKS + t] : 0u;
  s[t] = v;
  __syncthreads();
  for (int o = 1; o < 256; o <<= 1) {
    unsigned u = (t >= o) ? s[t - o] : 0u;
    __syncthreads();
    s[t] += u;
    __syncthreads();
  }
  if (t < CHUNKS) cnt[b * CHUNKS + t] = s[t] - v;
}

// ---------------- K4c: stable mask write (ties by ascending index)
__global__ __launch_bounds__(256) void k_maskw(const float* __restrict__ m,
    const float* __restrict__ x,
    const unsigned* __restrict__ selT, const int* __restrict__ selNeed,
    const unsigned* __restrict__ cnt,
    f16* __restrict__ mx, f16* __restrict__ mk) {
  int b = blockIdx.y, ch = blockIdx.x, t = threadIdx.x;
  int lane = t & 63, wv = t >> 6;
  unsigned T = selT[b];
  int need = selNeed[b];
  size_t i = (size_t)b * NP + ch * 256 + t;
  unsigned bits = __float_as_uint(m[i]);
  bool gt = bits > T, eq = bits == T;
  unsigned long long em = __ballot(eq);
  __shared__ unsigned wc[4];
  if (lane == 0) wc[wv] = (unsigned)__popcll(em);
  __syncthreads();
  int base = (int)cnt[b * CHUNKS + ch];
  for (int w = 0; w < wv; w++) base += (int)wc[w];
  int rank = (int)__popcll(em & ((1ULL << lane) - 1ULL));
  bool sel = gt || (eq && (base + rank) < need);
  mk[i] = sel ? (f16)1.f : (f16)0.f;
  mx[i] = sel ? (f16)x[i] : (f16)0.f;
}

// ======== Fused depthwise + pointwise(BN,relu) per level ========
// Block: 64 ci x (32 px wide x 4 DIL-strided rows). Thread = 1 ci, 8 px x 4 rows
// (dw4's proven inner loop), results staged to swizzled LDS, then pwm's MFMA phase.

// ---------------- lvl0: dw input = mx/mk planes (affine-K trick)
__global__ __launch_bounds__(256) void k_fused0(const float* __restrict__ dw_w,
    const float* __restrict__ w_in, const float* __restrict__ b_in,
    const f16* __restrict__ mx, const f16* __restrict__ mk,
    const float* __restrict__ pw_w, const float* __restrict__ pw_b,
    const float* __restrict__ g, const float* __restrict__ be,
    const float* __restrict__ mu, const float* __restrict__ var,
    f16* __restrict__ outp) {
  constexpr int LOFF = 8, NLD = 3;
  __shared__ f16 buf[128 * LDR];
  __shared__ float sc[64], sh[64];
  int t = threadIdx.x;
  if (t < 64) {
    float s = g[t] / sqrtf(var[t] + 1e-5f);
    sc[t] = s;
    sh[t] = (pw_b[t] - mu[t]) * s + be[t];
  }
  int b = blockIdx.y;
  int wgrp = blockIdx.x % 7, rowg = blockIdx.x / 7;  // rowg 0..55
  int h0 = rowg * 4;
  int ci = t & 63, w8l = t >> 6;
  int wbase = wgrp * 32 + w8l * 8;
  const f16* mxb = mx + (size_t)b * NP;
  const f16* mkb = mk + (size_t)b * NP;
  float kw = w_in[64 + ci], kb = b_in[64 + ci];
  const float* wp = dw_w + ci * 9;
  float wa[9], wb[9];
#pragma unroll
  for (int i = 0; i < 9; i++) {
    float wv_ = wp[i];
    wa[i] = wv_ * kw;
    wb[i] = wv_ * kb;
  }
  float acc[4][8] = {};
#pragma unroll
  for (int m = 0; m < 6; m++) {
    int him = h0 + m - 1;
    if ((unsigned)him >= (unsigned)HH) continue;
    float rx[NLD * 8], rk[NLD * 8];
    const f16* rpx = mxb + him * WW + (wbase - LOFF);
    const f16* rpk = mkb + him * WW + (wbase - LOFF);
#pragma unroll
    for (int s = 0; s < NLD; s++) {
      int ws_ = wbase - LOFF + s * 8;
      if ((unsigned)ws_ < (unsigned)WW) {
        f16x8 vx = *(const f16x8*)(rpx + s * 8);
        f16x8 vk = *(const f16x8*)(rpk + s * 8);
#pragma unroll
        for (int j = 0; j < 8; j++) { rx[s * 8 + j] = (float)vx[j]; rk[s * 8 + j] = (float)vk[j]; }
      } else {
#pragma unroll
        for (int j = 0; j < 8; j++) { rx[s * 8 + j] = 0.f; rk[s * 8 + j] = 0.f; }
      }
    }
#pragma unroll
    for (int j = 0; j < 4; j++) {
      int k = m - j;
      if ((unsigned)k >= 3u) continue;
#pragma unroll
      for (int kx = 0; kx < 3; kx++) {
        float a_ = wa[k * 3 + kx], b_ = wb[k * 3 + kx];
#pragma unroll
        for (int p = 0; p < 8; p++) {
          int idx = p + LOFF + (kx - 1);
          acc[j][p] = fmaf(a_, rx[idx], fmaf(b_, rk[idx], acc[j][p]));
        }
      }
    }
  }
  // stage to LDS: px_local = j*32 + w8l*8 + p  (64 lanes -> 64 ci, 2-way free)
#pragma unroll
  for (int j = 0; j < 4; j++)
#pragma unroll
    for (int p = 0; p < 8; p++)
      buf[BIDX(j * 32 + w8l * 8 + p, ci)] = (f16)acc[j][p];
  __syncthreads();
  // ---- pw phase (pwm's MFMA) ----
  int ln = t & 63, wv = t >> 6;
  int r16 = ln & 15, g4 = ln >> 4;
  f16x8 af[4][2];
#pragma unroll
  for (int cb = 0; cb < 4; cb++)
#pragma unroll
    for (int ks = 0; ks < 2; ks++) {
      const float* wr = pw_w + (cb * 16 + r16) * 64 + ks * 32 + g4 * 8;
      f32x4 w0 = *(const f32x4*)wr;
      f32x4 w1 = *(const f32x4*)(wr + 4);
      f16x8 a;
      a[0] = (f16)w0[0]; a[1] = (f16)w0[1]; a[2] = (f16)w0[2]; a[3] = (f16)w0[3];
      a[4] = (f16)w1[0]; a[5] = (f16)w1[1]; a[6] = (f16)w1[2]; a[7] = (f16)w1[3];
      af[cb][ks] = a;
    }
#pragma unroll
  for (int pxb = 0; pxb < 2; pxb++) {
    int pl = wv * 32 + pxb * 16;
    f16x8 bf[2];
#pragma unroll
    for (int ks = 0; ks < 2; ks++)
      bf[ks] = *(const f16x8*)&buf[BIDX(pl + r16, ks * 32 + g4 * 8)];
    f32x4 acc2[4];
#pragma unroll
    for (int cb = 0; cb < 4; cb++) acc2[cb] = (f32x4){0.f, 0.f, 0.f, 0.f};
#pragma unroll
    for (int cb = 0; cb < 4; cb++)
#pragma unroll
      for (int ks = 0; ks < 2; ks++)
        acc2[cb] = __builtin_amdgcn_mfma_f32_16x16x32_f16(af[cb][ks], bf[ks], acc2[cb], 0, 0, 0);
    int jrow = pl >> 5;                    // fragment-constant row index
    int wloc = (pl & 31) + r16;
    f16* dst = outp + (size_t)b * 64 * NP + (h0 + jrow) * WW + wgrp * 32 + wloc;
#pragma unroll
    for (int cb = 0; cb < 4; cb++)
#pragma unroll
      for (int j = 0; j < 4; j++) {
        int co = cb * 16 + g4 * 4 + j;
        float o = fmaf(acc2[cb][j], sc[co], sh[co]);
        dst[(size_t)co * NP] = (f16)fmaxf(o, 0.f);
      }
  }
}

// ---------------- lvl1/2: dw input = previous focal level
template <int KSZ, int DIL>
__global__ __launch_bounds__(256) void k_fused(const float* __restrict__ dw_w,
    const f16* __restrict__ fin,
    const float* __restrict__ pw_w, const float* __restrict__ pw_b,
    const float* __restrict__ g, const float* __restrict__ be,
    const float* __restrict__ mu, const float* __restrict__ var,
    f16* __restrict__ outp) {
  constexpr int PAD = (KSZ / 2) * DIL;
  constexpr int LOFF = (PAD + 7) & ~7;
  constexpr int NLD = (LOFF + 8 + PAD + 7) / 8;
  constexpr int NR = KSZ + 3;
  __shared__ f16 buf[128 * LDR];
  __shared__ float sc[64], sh[64];
  int t = threadIdx.x;
  if (t < 64) {
    float s = g[t] / sqrtf(var[t] + 1e-5f);
    sc[t] = s;
    sh[t] = (pw_b[t] - mu[t]) * s + be[t];
  }
  int b = blockIdx.y;
  int wgrp = blockIdx.x % 7, rowg = blockIdx.x / 7;
  int res = rowg % DIL, grp = rowg / DIL;
  int h0 = res + DIL * 4 * grp;
  int ci = t & 63, w8l = t >> 6;
  int wbase = wgrp * 32 + w8l * 8;
  const f16* fb = fin + (size_t)(b * 64 + ci) * NP;
  const float* wp = dw_w + ci * KSZ * KSZ;
  float wr_[KSZ * KSZ];
#pragma unroll
  for (int i = 0; i < KSZ * KSZ; i++) wr_[i] = wp[i];
  float acc[4][8] = {};
#pragma unroll
  for (int m = 0; m < NR; m++) {
    int him = h0 + (m - KSZ / 2) * DIL;
    if ((unsigned)him >= (unsigned)HH) continue;
    float r[NLD * 8];
    const f16* rp = fb + him * WW + (wbase - LOFF);
#pragma unroll
    for (int s = 0; s < NLD; s++) {
      int ws_ = wbase - LOFF + s * 8;
      if ((unsigned)ws_ < (unsigned)WW) {
        f16x8 v = *(const f16x8*)(rp + s * 8);
#pragma unroll
        for (int j = 0; j < 8; j++) r[s * 8 + j] = (float)v[j];
      } else {
#pragma unroll
        for (int j = 0; j < 8; j++) r[s * 8 + j] = 0.f;
      }
    }
#pragma unroll
    for (int j = 0; j < 4; j++) {
      int k = m - j;
      if (k < 0 || k >= KSZ) continue;
#pragma unroll
      for (int kx = 0; kx < KSZ; kx++) {
        float wv_ = wr_[k * KSZ + kx];
#pragma unroll
        for (int p = 0; p < 8; p++)
          acc[j][p] = fmaf(wv_, r[p + LOFF + (kx - KSZ / 2) * DIL], acc[j][p]);
      }
    }
  }
#pragma unroll
  for (int j = 0; j < 4; j++)
#pragma unroll
    for (int p = 0; p < 8; p++)
      buf[BIDX(j * 32 + w8l * 8 + p, ci)] = (f16)acc[j][p];
  __syncthreads();
  int ln = t & 63, wv = t >> 6;
  int r16 = ln & 15, g4 = ln >> 4;
  f16x8 af[4][2];
#pragma unroll
  for (int cb = 0; cb < 4; cb++)
#pragma unroll
    for (int ks = 0; ks < 2; ks++) {
      const float* wr = pw_w + (cb * 16 + r16) * 64 + ks * 32 + g4 * 8;
      f32x4 w0 = *(const f32x4*)wr;
      f32x4 w1 = *(const f32x4*)(wr + 4);
      f16x8 a;
      a[0] = (f16)w0[0]; a[1] = (f16)w0[1]; a[2] = (f16)w0[2]; a[3] = (f16)w0[3];
      a[4] = (f16)w1[0]; a[5] = (f16)w1[1]; a[6] = (f16)w1[2]; a[7] = (f16)w1[3];
      af[cb][ks] = a;
    }
#pragma unroll
  for (int pxb = 0; pxb < 2; pxb++) {
    int pl = wv * 32 + pxb * 16;
    f16x8 bf[2];
#pragma unroll
    for (int ks = 0; ks < 2; ks++)
      bf[ks] = *(const f16x8*)&buf[BIDX(pl + r16, ks * 32 + g4 * 8)];
    f32x4 acc2[4];
#pragma unroll
    for (int cb = 0; cb < 4; cb++) acc2[cb] = (f32x4){0.f, 0.f, 0.f, 0.f};
#pragma unroll
    for (int cb = 0; cb < 4; cb++)
#pragma unroll
      for (int ks = 0; ks < 2; ks++)
        acc2[cb] = __builtin_amdgcn_mfma_f32_16x16x32_f16(af[cb][ks], bf[ks], acc2[cb], 0, 0, 0);
    int jrow = pl >> 5;
    int wloc = (pl & 31) + r16;
    f16* dst = outp + (size_t)b * 64 * NP + (h0 + DIL * jrow) * WW + wgrp * 32 + wloc;
#pragma unroll
    for (int cb = 0; cb < 4; cb++)
#pragma unroll
      for (int j = 0; j < 4; j++) {
        int co = cb * 16 + g4 * 4 + j;
        float o = fmaf(acc2[cb][j], sc[co], sh[co]);
        dst[(size_t)co * NP] = (f16)fmaxf(o, 0.f);
      }
  }
}

// ---------------- K7: K_global = mean over pixels of focal[2]
__global__ __launch_bounds__(256) void k_mean(const f16* __restrict__ F2,
                                              float* __restrict__ kg) {
  int bc = blockIdx.x;
  const f16* f = F2 + (size_t)bc * NP;
  float s = 0.f;
  for (int i = threadIdx.x; i < NP; i += 256) s += (float)f[i];
  __shared__ float r[256];
  r[threadIdx.x] = s;
  __syncthreads();
  for (int o = 128; o > 0; o >>= 1) {
    if (threadIdx.x < o) r[threadIdx.x] += r[threadIdx.x + o];
    __syncthreads();
  }
  if (threadIdx.x == 0) kg[bc] = r[0] * (1.f / NP);
}

// ---------------- K8: fused K_final -> V -> QV -> out
__global__ __launch_bounds__(256) void k_final(const float* __restrict__ x,
    const float* __restrict__ w_in, const float* __restrict__ b_in,
    const f16* __restrict__ F0, const f16* __restrict__ F1, const f16* __restrict__ F2,
    const float* __restrict__ kg, const float* __restrict__ fcA,
    const float* __restrict__ bDg,
    const float* __restrict__ v_w, const float* __restrict__ v_b,
    const float* __restrict__ out_w,
    float* __restrict__ outp) {
  __shared__ f16 buf[128 * LDR];
  __shared__ float gvs[128 * 4];  // row r = gv for px = IROT(r)
  __shared__ float xs[128];
  __shared__ float kgs[64], qwS[64], qbS[64], vbS[64], bD[64], fcAS[64];
  int t = threadIdx.x;
  int b = blockIdx.y;
  int p0 = blockIdx.x * 128;
  if (t < 64) {
    kgs[t] = kg[b * 64 + t];
    qwS[t] = w_in[t];
    qbS[t] = b_in[t];
    vbS[t] = v_b[t];
    fcAS[t] = fcA[t];
    bD[t] = bDg[t];
  }
  if (t < 128) {
    int px = ((t & 15) << 3) | (t >> 4);  // IROT(t)
    float xv = x[(size_t)b * NP + p0 + px];
    xs[px] = xv;
    float gv[4], mxv = -1e30f;
#pragma unroll
    for (int j = 0; j < 4; j++) {
      gv[j] = fmaf(xv, w_in[128 + j], b_in[128 + j]);
      mxv = fmaxf(mxv, gv[j]);
    }
    float se = 0.f;
#pragma unroll
    for (int j = 0; j < 4; j++) { gv[j] = expf(gv[j] - mxv); se += gv[j]; }
    float inv = 1.f / se;
    f32x4 g4v;
#pragma unroll
    for (int j = 0; j < 4; j++) g4v[j] = gv[j] * inv;
    *(f32x4*)&gvs[t * 4] = g4v;
  }
  const f16* f0 = F0 + (size_t)b * 64 * NP + p0;
  const f16* f1 = F1 + (size_t)b * 64 * NP + p0;
  const f16* f2 = F2 + (size_t)b * 64 * NP + p0;
  f16x8 s0[4], s1[4], s2[4];
  int cis[4], pxs[4];
#pragma unroll
  for (int it = 0; it < 4; it++) {
    int cidx = it * 256 + t;
    cis[it] = cidx >> 4;
    pxs[it] = (cidx & 15) * 8;
    size_t o = (size_t)cis[it] * NP + pxs[it];
    s0[it] = *(const f16x8*)(f0 + o);
    s1[it] = *(const f16x8*)(f1 + o);
    s2[it] = *(const f16x8*)(f2 + o);
  }
  int ln = t & 63, wv = t >> 6;
  int r16 = ln & 15, g4 = ln >> 4;
  f16x8 afV[4][2];
#pragma unroll
  for (int cb = 0; cb < 4; cb++)
#pragma unroll
    for (int ks = 0; ks < 2; ks++) {
      const float* wr = v_w + (cb * 16 + r16) * 64 + ks * 32 + g4 * 8;
      f32x4 w0 = *(const f32x4*)wr;
      f32x4 w1 = *(const f32x4*)(wr + 4);
      f16x8 a;
      a[0] = (f16)w0[0]; a[1] = (f16)w0[1]; a[2] = (f16)w0[2]; a[3] = (f16)w0[3];
      a[4] = (f16)w1[0]; a[5] = (f16)w1[1]; a[6] = (f16)w1[2]; a[7] = (f16)w1[3];
      afV[cb][ks] = a;
    }
  __syncthreads();
#pragma unroll
  for (int it = 0; it < 4; it++) {
    int ci = cis[it], px8 = pxs[it];
    float kgc = kgs[ci];
#pragma unroll
    for (int j = 0; j < 8; j++) {
      int px = px8 + j;
      f32x4 gv = *(const f32x4*)&gvs[(((px & 7) << 4) | (px >> 3)) * 4];
      float kf = gv[0] * (float)s0[it][j] + gv[1] * (float)s1[it][j] +
                 gv[2] * (float)s2[it][j] + gv[3] * kgc;
      buf[BIDX(px, ci)] = (f16)kf;
    }
  }
  __syncthreads();
  {
#pragma unroll
    for (int pxb = 0; pxb < 2; pxb++) {
      int pl = wv * 32 + pxb * 16;
      f16x8 bf[2];
#pragma unroll
      for (int ks = 0; ks < 2; ks++)
        bf[ks] = *(const f16x8*)&buf[BIDX(pl + r16, ks * 32 + g4 * 8)];
      f32x4 acc[4];
#pragma unroll
      for (int cb = 0; cb < 4; cb++) acc[cb] = (f32x4){0.f, 0.f, 0.f, 0.f};
#pragma unroll
      for (int cb = 0; cb < 4; cb++)
#pragma unroll
        for (int ks = 0; ks < 2; ks++)
          acc[cb] = __builtin_amdgcn_mfma_f32_16x16x32_f16(afV[cb][ks], bf[ks], acc[cb], 0, 0, 0);
      int px = pl + r16;
      float xv = xs[px];
#pragma unroll
      for (int cb = 0; cb < 4; cb++) {
        f16x4 q4;
#pragma unroll
        for (int j = 0; j < 4; j++) {
          int co = cb * 16 + g4 * 4 + j;
          float V = acc[cb][j] + vbS[co];
          float q = fmaf(xv, qwS[co], qbS[co]);
          q4[j] = (f16)(q * V);
        }
        *(f16x4*)&buf[BIDX(px, cb * 16 + g4 * 4)] = q4;
      }
    }
  }
  f16x8 afO[4][2];
#pragma unroll
  for (int cb = 0; cb < 4; cb++)
#pragma unroll
    for (int ks = 0; ks < 2; ks++) {
      const float* wr = out_w + (cb * 16 + r16) * 64 + ks * 32 + g4 * 8;
      f32x4 w0 = *(const f32x4*)wr;
      f32x4 w1 = *(const f32x4*)(wr + 4);
      f16x8 a;
      a[0] = (f16)w0[0]; a[1] = (f16)w0[1]; a[2] = (f16)w0[2]; a[3] = (f16)w0[3];
      a[4] = (f16)w1[0]; a[5] = (f16)w1[1]; a[6] = (f16)w1[2]; a[7] = (f16)w1[3];
      afO[cb][ks] = a;
    }
  __syncthreads();
  {
#pragma unroll
    for (int pxb = 0; pxb < 2; pxb++) {
      int pl = wv * 32 + pxb * 16;
      f16x8 bf[2];
#pragma unroll
      for (int ks = 0; ks < 2; ks++)
        bf[ks] = *(const f16x8*)&buf[BIDX(pl + r16, ks * 32 + g4 * 8)];
      f32x4 acc[4];
#pragma unroll
      for (int cb = 0; cb < 4; cb++) acc[cb] = (f32x4){0.f, 0.f, 0.f, 0.f};
#pragma unroll
      for (int cb = 0; cb < 4; cb++)
#pragma unroll
        for (int ks = 0; ks < 2; ks++)
          acc[cb] = __builtin_amdgcn_mfma_f32_16x16x32_f16(afO[cb][ks], bf[ks], acc[cb], 0, 0, 0);
      int px = pl + r16;
      float xv = xs[px];
      float* dst = outp + (size_t)b * 64 * NP + p0 + px;
#pragma unroll
      for (int cb = 0; cb < 4; cb++)
#pragma unroll
        for (int j = 0; j < 4; j++) {
          int d = cb * 16 + g4 * 4 + j;
          dst[(size_t)d * NP] = acc[cb][j] + bD[d] + xv * fcAS[d];
        }
    }
  }
}

extern "C" void kernel_launch(void* const* d_in, const int* in_sizes, int n_in,
                              void* d_out, int out_size, void* d_ws, size_t ws_size,
                              hipStream_t stream) {
  const float* x = (const float*)d_in[0];
  const float* w_in = (const float*)d_in[1];
  const float* b_in = (const float*)d_in[2];
  const float* dw_w[3] = {(const float*)d_in[3], (const float*)d_in[10], (const float*)d_in[17]};
  const float* pw_w[3] = {(const float*)d_in[4], (const float*)d_in[11], (const float*)d_in[18]};
  const float* pw_b[3] = {(const float*)d_in[5], (const float*)d_in[12], (const float*)d_in[19]};
  const float* bng[3] = {(const float*)d_in[6], (const float*)d_in[13], (const float*)d_in[20]};
  const float* bnb[3] = {(const float*)d_in[7], (const float*)d_in[14], (const float*)d_in[21]};
  const float* bnm[3] = {(const float*)d_in[8], (const float*)d_in[15], (const float*)d_in[22]};
  const float* bnv[3] = {(const float*)d_in[9], (const float*)d_in[16], (const float*)d_in[23]};
  const float* imp1_w = (const float*)d_in[24];
  const float* imp1_b = (const float*)d_in[25];
  const float* imp2_w = (const float*)d_in[26];
  const float* imp2_b = (const float*)d_in[27];
  const float* v_w = (const float*)d_in[28];
  const float* v_b = (const float*)d_in[29];
  const float* out_w = (const float*)d_in[30];
  const float* out_b = (const float*)d_in[31];
  const float* fc_w = (const float*)d_in[32];
  const float* fc_b = (const float*)d_in[33];

  char* ws = (char*)d_ws;
  size_t off = 0;
  auto alloc = [&](size_t sz) {
    size_t o = off;
    off = (off + sz + 255) & ~(size_t)255;
    return o;
  };
  float* mbuf = (float*)(ws + alloc((size_t)BB * NP * 4));
  unsigned* ghist = (unsigned*)(ws + alloc((size_t)BB * 2048 * 4));
  unsigned* prefix = (unsigned*)(ws + alloc(8 * 4));
  int* remv = (int*)(ws + alloc(8 * 4));
  unsigned* selT = (unsigned*)(ws + alloc(8 * 4));
  int* selNeed = (int*)(ws + alloc(8 * 4));
  unsigned* cntbuf = (unsigned*)(ws + alloc((size_t)BB * CHUNKS * 4));
  float* fcA = (float*)(ws + alloc(64 * 4));
  float* bDg = (float*)(ws + alloc(64 * 4));
  f16* mx = (f16*)(ws + alloc((size_t)BB * NP * 2));
  f16* mk = (f16*)(ws + alloc((size_t)BB * NP * 2));
  f16* F0 = (f16*)(ws + alloc((size_t)BB * 64 * NP * 2));
  f16* F1 = (f16*)(ws + alloc((size_t)BB * 64 * NP * 2));
  f16* F2 = (f16*)(ws + alloc((size_t)BB * 64 * NP * 2));
  float* kg = (float*)(ws + alloc(512 * 4));

  const int PIX_BLKS = (BB * NP) / 256;   // 1568
  dim3 tile_grid(NP / 128, BB);           // 392 x 8
  dim3 fuse_grid(392, BB);                // (7 wgrp x 56 rowg) x 8
  dim3 chunk_grid(CHUNKS, BB);            // 196 x 8
  dim3 hist_grid(HB, BB);                 // 28 x 8

  k_m<<<PIX_BLKS, 256, 0, stream>>>(x, w_in, b_in, imp1_w, imp1_b, imp2_w, imp2_b, mbuf);
  k_init<<<64, 256, 0, stream>>>(ghist, prefix, remv);
  k_setup<<<1, 64, 0, stream>>>(w_in, b_in, out_b, fc_w, fc_b, fcA, bDg);
  // 3-pass radix select: 11 + 11 + 10 bits
  k_hist<21, 0u, 2048><<<hist_grid, 256, 0, stream>>>(mbuf, prefix, ghist);
  k_pick<21, 2048, 0><<<BB, 256, 0, stream>>>(ghist, prefix, remv, selT, selNeed);
  k_hist<10, 0xFFE00000u, 2048><<<hist_grid, 256, 0, stream>>>(mbuf, prefix, ghist);
  k_pick<10, 2048, 0><<<BB, 256, 0, stream>>>(ghist, prefix, remv, selT, selNeed);
  k_hist<0, 0xFFFFFC00u, 1024><<<hist_grid, 256, 0, stream>>>(mbuf, prefix, ghist);
  k_pick<0, 1024, 1><<<BB, 256, 0, stream>>>(ghist, prefix, remv, selT, selNeed);

  k_cnteq<<<chunk_grid, 256, 0, stream>>>(mbuf, selT, cntbuf);
  k_scan<<<BB, 256, 0, stream>>>(cntbuf);
  k_maskw<<<chunk_grid, 256, 0, stream>>>(mbuf, x, selT, selNeed, cntbuf, mx, mk);

  // fused dw+pw per level
  k_fused0<<<fuse_grid, 256, 0, stream>>>(dw_w[0], w_in, b_in, mx, mk,
      pw_w[0], pw_b[0], bng[0], bnb[0], bnm[0], bnv[0], F0);
  k_fused<5, 2><<<fuse_grid, 256, 0, stream>>>(dw_w[1], F0,
      pw_w[1], pw_b[1], bng[1], bnb[1], bnm[1], bnv[1], F1);
  k_fused<7, 4><<<fuse_grid, 256, 0, stream>>>(dw_w[2], F1,
      pw_w[2], pw_b[2], bng[2], bnb[2], bnm[2], bnv[2], F2);

  k_mean<<<512, 256, 0, stream>>>(F2, kg);
  k_final<<<tile_grid, 256, 0, stream>>>(x, w_in, b_in, F0, F1, F2, kg, fcA, bDg,
                                         v_w, v_b, out_w, (float*)d_out);
}

// Round 16
// 414.856 us; speedup vs baseline: 1.1314x; 1.1314x over previous
//
#include <hip/hip_runtime.h>
#include <hip/hip_fp16.h>

typedef _Float16 f16;
typedef _Float16 f16x8 __attribute__((ext_vector_type(8)));
typedef _Float16 f16x4 __attribute__((ext_vector_type(4)));
typedef float f32x4 __attribute__((ext_vector_type(4)));

static constexpr int BB = 8, HH = 224, WW = 224, NP = HH * WW; // 50176
static constexpr int TOPK = 15052;  // max(int(0.3*224*224), 64)
static constexpr int LDR = 72;      // LDS row stride (f16)
static constexpr int CHUNKS = NP / 256;  // 196
static constexpr int HB = 28;       // hist blocks per batch; NP/HB = 1792

// XOR-swizzled LDS index for buf (fixes px8-strided scalar-write 16-way conflict).
__device__ __forceinline__ int BIDX(int px, int ci) {
  return px * LDR + (ci ^ (((px >> 3) & 7) << 3));
}

// ---------------- K2 (fused): m = sigmoid(conv3x3(relu(A_j x + B_j)) + b)
__global__ __launch_bounds__(256) void k_m(const float* __restrict__ x,
    const float* __restrict__ w_in, const float* __restrict__ b_in,
    const float* __restrict__ imp1_w, const float* __restrict__ imp1_b,
    const float* __restrict__ imp2_w, const float* __restrict__ imp2_b,
    float* __restrict__ m) {
  __shared__ float A[16], Bv[16], w2[144];
  __shared__ float bsh;
  int t = threadIdx.x;
  if (t < 144) w2[t] = imp2_w[t];
  if (t == 0) bsh = imp2_b[0];
  if (t < 16) {
    float a = 0.f, bb = 0.f;
    for (int c = 0; c < 64; c++) {
      float iw = imp1_w[t * 64 + c];
      a = fmaf(iw, w_in[64 + c], a);
      bb = fmaf(iw, b_in[64 + c], bb);
    }
    A[t] = a;
    Bv[t] = bb + imp1_b[t];
  }
  __syncthreads();
  int p = blockIdx.x * 256 + t;
  int b = p / NP, pp = p - b * NP;
  int h = pp / WW, w = pp - h * WW;
  const float* xb = x + (size_t)b * NP;
  float s = bsh;
#pragma unroll
  for (int ky = 0; ky < 3; ky++) {
    int hy = h + ky - 1;
    if ((unsigned)hy >= (unsigned)HH) continue;
#pragma unroll
    for (int kx = 0; kx < 3; kx++) {
      int wx = w + kx - 1;
      if ((unsigned)wx >= (unsigned)WW) continue;
      float xn = xb[hy * WW + wx];
#pragma unroll
      for (int j = 0; j < 16; j++) {
        float m1 = fmaxf(fmaf(A[j], xn, Bv[j]), 0.f);
        s = fmaf(w2[j * 9 + ky * 3 + kx], m1, s);
      }
    }
  }
  m[p] = 1.f / (1.f + expf(-s));
}

// ---------------- K_setup: block-invariant epilogue constants
__global__ __launch_bounds__(64) void k_setup(const float* __restrict__ w_in,
    const float* __restrict__ b_in, const float* __restrict__ out_b,
    const float* __restrict__ fc_w, const float* __restrict__ fc_b,
    float* __restrict__ fcA, float* __restrict__ bDg) {
  int d = threadIdx.x;
  float fa = 0.f, fb = 0.f;
  for (int c = 0; c < 64; c++) {
    float fw = fc_w[d * 64 + c];
    fa = fmaf(fw, w_in[c], fa);
    fb = fmaf(fw, b_in[c], fb);
  }
  fcA[d] = fa;
  bDg[d] = out_b[d] + fc_b[d] + fb;
}

// ---------------- K3a: init select state
__global__ __launch_bounds__(256) void k_init(unsigned* __restrict__ ghist,
    unsigned* __restrict__ prefix, int* __restrict__ rem) {
  int i = blockIdx.x * 256 + threadIdx.x;
  if (i < 8 * 2048) ghist[i] = 0u;
  if (i < 8) { prefix[i] = 0u; rem[i] = TOPK; }
}

// ---------------- K3b: grid-parallel histogram of one radix digit
template <int SHIFT, unsigned HIMASK, int BINS>
__global__ __launch_bounds__(256) void k_hist(const float* __restrict__ m,
    const unsigned* __restrict__ prefix, unsigned* __restrict__ ghist) {
  __shared__ unsigned hist[2048];
  int b = blockIdx.y, blk = blockIdx.x, t = threadIdx.x;
  for (int i = t; i < BINS; i += 256) hist[i] = 0u;
  __syncthreads();
  unsigned pfx = prefix[b];
  const float* mb = m + (size_t)b * NP + blk * (NP / HB);
#pragma unroll
  for (int it = 0; it < NP / HB / 256; it++) {
    unsigned bits = __float_as_uint(mb[it * 256 + t]);
    if ((bits & HIMASK) == pfx) atomicAdd(&hist[(bits >> SHIFT) & (BINS - 1)], 1u);
  }
  __syncthreads();
  unsigned* gh = ghist + b * 2048;
  for (int i = t; i < BINS; i += 256) {
    unsigned v = hist[i];
    if (v) atomicAdd(&gh[i], v);
  }
}

// ---------------- K3c: pick k-th bin via suffix scan; advance prefix/rem; zero ghist
template <int SHIFT, int BINS, int FINAL>
__global__ __launch_bounds__(256) void k_pick(unsigned* __restrict__ ghist,
    unsigned* __restrict__ prefix, int* __restrict__ rem,
    unsigned* __restrict__ selT, int* __restrict__ selNeed) {
  __shared__ unsigned s[256];
  int b = blockIdx.x, t = threadIdx.x;
  constexpr int PER = BINS / 256;
  unsigned* gh = ghist + b * 2048;
  unsigned local[PER];
  unsigned sum = 0;
#pragma unroll
  for (int j = 0; j < PER; j++) { local[j] = gh[t * PER + j]; sum += local[j]; }
#pragma unroll
  for (int j = 0; j < PER; j++) gh[t * PER + j] = 0u;
  s[t] = sum;
  int rm = rem[b];
  unsigned pfx = prefix[b];
  __syncthreads();
  for (int o = 1; o < 256; o <<= 1) {
    unsigned v = (t + o < 256) ? s[t + o] : 0u;
    __syncthreads();
    s[t] += v;
    __syncthreads();
  }
  unsigned nb = (t < 255) ? s[t + 1] : 0u;
  if (s[t] >= (unsigned)rm && nb < (unsigned)rm) {
    int acc = (int)nb;
#pragma unroll
    for (int j = PER - 1; j >= 0; j--) {
      acc += (int)local[j];
      if (acc >= rm) {
        unsigned bin = (unsigned)(t * PER + j);
        int need = rm - (acc - (int)local[j]);
        if (FINAL) {
          selT[b] = pfx | (bin << SHIFT);
          selNeed[b] = need;
        } else {
          prefix[b] = pfx | (bin << SHIFT);
          rem[b] = need;
        }
        break;
      }
    }
  }
}

// ---------------- K4a: per-chunk count of (bits == T)
__global__ __launch_bounds__(256) void k_cnteq(const float* __restrict__ m,
    const unsigned* __restrict__ selT, unsigned* __restrict__ cnt) {
  int b = blockIdx.y, ch = blockIdx.x, t = threadIdx.x;
  unsigned T = selT[b];
  unsigned bits = __float_as_uint(m[(size_t)b * NP + ch * 256 + t]);
  unsigned long long em = __ballot(bits == T);
  __shared__ unsigned wc[4];
  if ((t & 63) == 0) wc[t >> 6] = (unsigned)__popcll(em);
  __syncthreads();
  if (t == 0) cnt[b * CHUNKS + ch] = wc[0] + wc[1] + wc[2] + wc[3];
}

// ---------------- K4b: per-batch exclusive scan of chunk counts
__global__ __launch_bounds__(256) void k_scan(unsigned* __restrict__ cnt) {
  __shared__ unsigned s[256];
  int b = blockIdx.x, t = threadIdx.x;
  unsigned v = (t < CHUNKS) ? cnt[b * CHUNKS + t] : 0u;
  s[t] = v;
  __syncthreads();
  for (int o = 1; o < 256; o <<= 1) {
    unsigned u = (t >= o) ? s[t - o] : 0u;
    __syncthreads();
    s[t] += u;
    __syncthreads();
  }
  if (t < CHUNKS) cnt[b * CHUNKS + t] = s[t] - v;
}

// ---------------- K4c: stable mask write (ties by ascending index)
__global__ __launch_bounds__(256) void k_maskw(const float* __restrict__ m,
    const float* __restrict__ x,
    const unsigned* __restrict__ selT, const int* __restrict__ selNeed,
    const unsigned* __restrict__ cnt,
    f16* __restrict__ mx, f16* __restrict__ mk) {
  int b = blockIdx.y, ch = blockIdx.x, t = threadIdx.x;
  int lane = t & 63, wv = t >> 6;
  unsigned T = selT[b];
  int need = selNeed[b];
  size_t i = (size_t)b * NP + ch * 256 + t;
  unsigned bits = __float_as_uint(m[i]);
  bool gt = bits > T, eq = bits == T;
  unsigned long long em = __ballot(eq);
  __shared__ unsigned wc[4];
  if (lane == 0) wc[wv] = (unsigned)__popcll(em);
  __syncthreads();
  int base = (int)cnt[b * CHUNKS + ch];
  for (int w = 0; w < wv; w++) base += (int)wc[w];
  int rank = (int)__popcll(em & ((1ULL << lane) - 1ULL));
  bool sel = gt || (eq && (base + rank) < need);
  mk[i] = sel ? (f16)1.f : (f16)0.f;
  mx[i] = sel ? (f16)x[i] : (f16)0.f;
}

// ---------------- K5a: 4-row-grouped depthwise lvl0, weights in VGPRs, m unrolled
__global__ __launch_bounds__(256) void k_dw0(const float* __restrict__ dw_w,
    const float* __restrict__ w_in, const float* __restrict__ b_in,
    const f16* __restrict__ mx, const f16* __restrict__ mk,
    f16* __restrict__ outp) {
  constexpr int LOFF = 8, NLD = 3;
  int g = blockIdx.x * 256 + threadIdx.x;
  int w8 = g % 28;
  int rem = g / 28;
  int rowg = rem % 56, bc = rem / 56;
  int b = bc >> 6, c = bc & 63;
  int w0 = w8 * 8;
  int h0 = rowg * 4;
  const f16* mxb = mx + (size_t)b * NP;
  const f16* mkb = mk + (size_t)b * NP;
  float kw = w_in[64 + c], kb = b_in[64 + c];
  const float* wp = dw_w + c * 9;
  float wa[9], wb[9];
#pragma unroll
  for (int i = 0; i < 9; i++) {
    float wv = wp[i];
    wa[i] = wv * kw;
    wb[i] = wv * kb;
  }
  float acc[4][8] = {};
#pragma unroll
  for (int m = 0; m < 6; m++) {
    int him = h0 + m - 1;
    if ((unsigned)him >= (unsigned)HH) continue;
    float rx[NLD * 8], rk[NLD * 8];
    const f16* rpx = mxb + him * WW + (w0 - LOFF);
    const f16* rpk = mkb + him * WW + (w0 - LOFF);
#pragma unroll
    for (int s = 0; s < NLD; s++) {
      int ws_ = w0 - LOFF + s * 8;
      if ((unsigned)ws_ < (unsigned)WW) {
        f16x8 vx = *(const f16x8*)(rpx + s * 8);
        f16x8 vk = *(const f16x8*)(rpk + s * 8);
#pragma unroll
        for (int j = 0; j < 8; j++) { rx[s * 8 + j] = (float)vx[j]; rk[s * 8 + j] = (float)vk[j]; }
      } else {
#pragma unroll
        for (int j = 0; j < 8; j++) { rx[s * 8 + j] = 0.f; rk[s * 8 + j] = 0.f; }
      }
    }
#pragma unroll
    for (int j = 0; j < 4; j++) {
      constexpr unsigned K3 = 3u;
      int k = m - j;
      if ((unsigned)k >= K3) continue;
#pragma unroll
      for (int kx = 0; kx < 3; kx++) {
        float a_ = wa[k * 3 + kx], b_ = wb[k * 3 + kx];
#pragma unroll
        for (int p = 0; p < 8; p++) {
          int idx = p + LOFF + (kx - 1);
          acc[j][p] = fmaf(a_, rx[idx], fmaf(b_, rk[idx], acc[j][p]));
        }
      }
    }
  }
#pragma unroll
  for (int j = 0; j < 4; j++) {
    f16x8 o;
#pragma unroll
    for (int p = 0; p < 8; p++) o[p] = (f16)acc[j][p];
    *(f16x8*)(outp + (size_t)bc * NP + (h0 + j) * WW + w0) = o;
  }
}

// ---------------- K5b: 4-row-grouped depthwise lvl1/2, weights in VGPRs, m unrolled
template <int KSZ, int DIL>
__global__ __launch_bounds__(256) void k_dw4(const float* __restrict__ dw_w,
    const f16* __restrict__ fin, f16* __restrict__ outp) {
  constexpr int PAD = (KSZ / 2) * DIL;
  constexpr int LOFF = (PAD + 7) & ~7;
  constexpr int NLD = (LOFF + 8 + PAD + 7) / 8;
  constexpr int NR = KSZ + 3;
  int g = blockIdx.x * 256 + threadIdx.x;
  int w8 = g % 28;
  int rem = g / 28;
  int rowg = rem % 56, bc = rem / 56;
  int w0 = w8 * 8;
  int res = rowg % DIL, grp = rowg / DIL;
  int h0 = res + DIL * 4 * grp;
  int c = bc & 63;
  const f16* fb = fin + (size_t)bc * NP;
  const float* wp = dw_w + c * KSZ * KSZ;
  float wr[KSZ * KSZ];
#pragma unroll
  for (int i = 0; i < KSZ * KSZ; i++) wr[i] = wp[i];
  float acc[4][8] = {};
#pragma unroll
  for (int m = 0; m < NR; m++) {
    int him = h0 + (m - KSZ / 2) * DIL;
    if ((unsigned)him >= (unsigned)HH) continue;
    float r[NLD * 8];
    const f16* rp = fb + him * WW + (w0 - LOFF);
#pragma unroll
    for (int s = 0; s < NLD; s++) {
      int ws_ = w0 - LOFF + s * 8;
      if ((unsigned)ws_ < (unsigned)WW) {
        f16x8 v = *(const f16x8*)(rp + s * 8);
#pragma unroll
        for (int j = 0; j < 8; j++) r[s * 8 + j] = (float)v[j];
      } else {
#pragma unroll
        for (int j = 0; j < 8; j++) r[s * 8 + j] = 0.f;
      }
    }
#pragma unroll
    for (int j = 0; j < 4; j++) {
      int k = m - j;
      if (k < 0 || k >= KSZ) continue;
#pragma unroll
      for (int kx = 0; kx < KSZ; kx++) {
        float wv = wr[k * KSZ + kx];
#pragma unroll
        for (int p = 0; p < 8; p++)
          acc[j][p] = fmaf(wv, r[p + LOFF + (kx - KSZ / 2) * DIL], acc[j][p]);
      }
    }
  }
#pragma unroll
  for (int j = 0; j < 4; j++) {
    f16x8 o;
#pragma unroll
    for (int p = 0; p < 8; p++) o[p] = (f16)acc[j][p];
    *(f16x8*)(outp + (size_t)bc * NP + (h0 + DIL * j) * WW + w0) = o;
  }
}

// ---------------- K6: MFMA pointwise 64x64 + folded BN + relu (swizzled LDS)
__global__ __launch_bounds__(256) void k_pwm(const f16* __restrict__ inp,
    const float* __restrict__ pw_w, const float* __restrict__ pw_b,
    const float* __restrict__ g, const float* __restrict__ be,
    const float* __restrict__ mu, const float* __restrict__ var,
    f16* __restrict__ outp) {
  __shared__ f16 buf[128 * LDR];
  __shared__ float sc[64], sh[64];
  int t = threadIdx.x;
  if (t < 64) {
    float s = g[t] / sqrtf(var[t] + 1e-5f);
    sc[t] = s;
    sh[t] = (pw_b[t] - mu[t]) * s + be[t];
  }
  int b = blockIdx.y;
  int p0 = blockIdx.x * 128;
  const f16* src = inp + (size_t)b * 64 * NP + p0;
  f16x8 vv[4];
  int cis[4], pxs[4];
#pragma unroll
  for (int it = 0; it < 4; it++) {
    int cidx = it * 256 + t;
    cis[it] = cidx >> 4;
    pxs[it] = (cidx & 15) * 8;
    vv[it] = *(const f16x8*)(src + (size_t)cis[it] * NP + pxs[it]);
  }
#pragma unroll
  for (int it = 0; it < 4; it++) {
#pragma unroll
    for (int j = 0; j < 8; j++) buf[BIDX(pxs[it] + j, cis[it])] = vv[it][j];
  }
  __syncthreads();
  int ln = t & 63, wv = t >> 6;
  int r16 = ln & 15, g4 = ln >> 4;
  f16x8 af[4][2];
#pragma unroll
  for (int cb = 0; cb < 4; cb++)
#pragma unroll
    for (int ks = 0; ks < 2; ks++) {
      const float* wr = pw_w + (cb * 16 + r16) * 64 + ks * 32 + g4 * 8;
      f32x4 w0 = *(const f32x4*)wr;
      f32x4 w1 = *(const f32x4*)(wr + 4);
      f16x8 a;
      a[0] = (f16)w0[0]; a[1] = (f16)w0[1]; a[2] = (f16)w0[2]; a[3] = (f16)w0[3];
      a[4] = (f16)w1[0]; a[5] = (f16)w1[1]; a[6] = (f16)w1[2]; a[7] = (f16)w1[3];
      af[cb][ks] = a;
    }
#pragma unroll
  for (int pxb = 0; pxb < 2; pxb++) {
    int pl = wv * 32 + pxb * 16;
    f16x8 bf[2];
#pragma unroll
    for (int ks = 0; ks < 2; ks++)
      bf[ks] = *(const f16x8*)&buf[BIDX(pl + r16, ks * 32 + g4 * 8)];
    f32x4 acc[4];
#pragma unroll
    for (int cb = 0; cb < 4; cb++) acc[cb] = (f32x4){0.f, 0.f, 0.f, 0.f};
#pragma unroll
    for (int cb = 0; cb < 4; cb++)
#pragma unroll
      for (int ks = 0; ks < 2; ks++)
        acc[cb] = __builtin_amdgcn_mfma_f32_16x16x32_f16(af[cb][ks], bf[ks], acc[cb], 0, 0, 0);
    f16* dst = outp + (size_t)b * 64 * NP + p0 + pl + r16;
#pragma unroll
    for (int cb = 0; cb < 4; cb++)
#pragma unroll
      for (int j = 0; j < 4; j++) {
        int co = cb * 16 + g4 * 4 + j;
        float o = fmaf(acc[cb][j], sc[co], sh[co]);
        dst[(size_t)co * NP] = (f16)fmaxf(o, 0.f);
      }
  }
}

// ---------------- K7: K_global = mean over pixels of focal[2]
__global__ __launch_bounds__(256) void k_mean(const f16* __restrict__ F2,
                                              float* __restrict__ kg) {
  int bc = blockIdx.x;
  const f16* f = F2 + (size_t)bc * NP;
  float s = 0.f;
  for (int i = threadIdx.x; i < NP; i += 256) s += (float)f[i];
  __shared__ float r[256];
  r[threadIdx.x] = s;
  __syncthreads();
  for (int o = 128; o > 0; o >>= 1) {
    if (threadIdx.x < o) r[threadIdx.x] += r[threadIdx.x + o];
    __syncthreads();
  }
  if (threadIdx.x == 0) kg[bc] = r[0] * (1.f / NP);
}

// ---------------- K8: fused K_final -> V -> QV -> out
__global__ __launch_bounds__(256) void k_final(const float* __restrict__ x,
    const float* __restrict__ w_in, const float* __restrict__ b_in,
    const f16* __restrict__ F0, const f16* __restrict__ F1, const f16* __restrict__ F2,
    const float* __restrict__ kg, const float* __restrict__ fcA,
    const float* __restrict__ bDg,
    const float* __restrict__ v_w, const float* __restrict__ v_b,
    const float* __restrict__ out_w,
    float* __restrict__ outp) {
  __shared__ f16 buf[128 * LDR];
  __shared__ float gvs[128 * 4];  // row r = gv for px = IROT(r)
  __shared__ float xs[128];
  __shared__ float kgs[64], qwS[64], qbS[64], vbS[64], bD[64], fcAS[64];
  int t = threadIdx.x;
  int b = blockIdx.y;
  int p0 = blockIdx.x * 128;
  if (t < 64) {
    kgs[t] = kg[b * 64 + t];
    qwS[t] = w_in[t];
    qbS[t] = b_in[t];
    vbS[t] = v_b[t];
    fcAS[t] = fcA[t];
    bD[t] = bDg[t];
  }
  if (t < 128) {
    int px = ((t & 15) << 3) | (t >> 4);  // IROT(t)
    float xv = x[(size_t)b * NP + p0 + px];
    xs[px] = xv;
    float gv[4], mxv = -1e30f;
#pragma unroll
    for (int j = 0; j < 4; j++) {
      gv[j] = fmaf(xv, w_in[128 + j], b_in[128 + j]);
      mxv = fmaxf(mxv, gv[j]);
    }
    float se = 0.f;
#pragma unroll
    for (int j = 0; j < 4; j++) { gv[j] = expf(gv[j] - mxv); se += gv[j]; }
    float inv = 1.f / se;
    f32x4 g4v;
#pragma unroll
    for (int j = 0; j < 4; j++) g4v[j] = gv[j] * inv;
    *(f32x4*)&gvs[t * 4] = g4v;
  }
  const f16* f0 = F0 + (size_t)b * 64 * NP + p0;
  const f16* f1 = F1 + (size_t)b * 64 * NP + p0;
  const f16* f2 = F2 + (size_t)b * 64 * NP + p0;
  f16x8 s0[4], s1[4], s2[4];
  int cis[4], pxs[4];
#pragma unroll
  for (int it = 0; it < 4; it++) {
    int cidx = it * 256 + t;
    cis[it] = cidx >> 4;
    pxs[it] = (cidx & 15) * 8;
    size_t o = (size_t)cis[it] * NP + pxs[it];
    s0[it] = *(const f16x8*)(f0 + o);
    s1[it] = *(const f16x8*)(f1 + o);
    s2[it] = *(const f16x8*)(f2 + o);
  }
  int ln = t & 63, wv = t >> 6;
  int r16 = ln & 15, g4 = ln >> 4;
  f16x8 afV[4][2];
#pragma unroll
  for (int cb = 0; cb < 4; cb++)
#pragma unroll
    for (int ks = 0; ks < 2; ks++) {
      const float* wr = v_w + (cb * 16 + r16) * 64 + ks * 32 + g4 * 8;
      f32x4 w0 = *(const f32x4*)wr;
      f32x4 w1 = *(const f32x4*)(wr + 4);
      f16x8 a;
      a[0] = (f16)w0[0]; a[1] = (f16)w0[1]; a[2] = (f16)w0[2]; a[3] = (f16)w0[3];
      a[4] = (f16)w1[0]; a[5] = (f16)w1[1]; a[6] = (f16)w1[2]; a[7] = (f16)w1[3];
      afV[cb][ks] = a;
    }
  __syncthreads();
#pragma unroll
  for (int it = 0; it < 4; it++) {
    int ci = cis[it], px8 = pxs[it];
    float kgc = kgs[ci];
#pragma unroll
    for (int j = 0; j < 8; j++) {
      int px = px8 + j;
      f32x4 gv = *(const f32x4*)&gvs[(((px & 7) << 4) | (px >> 3)) * 4];
      float kf = gv[0] * (float)s0[it][j] + gv[1] * (float)s1[it][j] +
                 gv[2] * (float)s2[it][j] + gv[3] * kgc;
      buf[BIDX(px, ci)] = (f16)kf;
    }
  }
  __syncthreads();
  {
#pragma unroll
    for (int pxb = 0; pxb < 2; pxb++) {
      int pl = wv * 32 + pxb * 16;
      f16x8 bf[2];
#pragma unroll
      for (int ks = 0; ks < 2; ks++)
        bf[ks] = *(const f16x8*)&buf[BIDX(pl + r16, ks * 32 + g4 * 8)];
      f32x4 acc[4];
#pragma unroll
      for (int cb = 0; cb < 4; cb++) acc[cb] = (f32x4){0.f, 0.f, 0.f, 0.f};
#pragma unroll
      for (int cb = 0; cb < 4; cb++)
#pragma unroll
        for (int ks = 0; ks < 2; ks++)
          acc[cb] = __builtin_amdgcn_mfma_f32_16x16x32_f16(afV[cb][ks], bf[ks], acc[cb], 0, 0, 0);
      int px = pl + r16;
      float xv = xs[px];
#pragma unroll
      for (int cb = 0; cb < 4; cb++) {
        f16x4 q4;
#pragma unroll
        for (int j = 0; j < 4; j++) {
          int co = cb * 16 + g4 * 4 + j;
          float V = acc[cb][j] + vbS[co];
          float q = fmaf(xv, qwS[co], qbS[co]);
          q4[j] = (f16)(q * V);
        }
        *(f16x4*)&buf[BIDX(px, cb * 16 + g4 * 4)] = q4;
      }
    }
  }
  f16x8 afO[4][2];
#pragma unroll
  for (int cb = 0; cb < 4; cb++)
#pragma unroll
    for (int ks = 0; ks < 2; ks++) {
      const float* wr = out_w + (cb * 16 + r16) * 64 + ks * 32 + g4 * 8;
      f32x4 w0 = *(const f32x4*)wr;
      f32x4 w1 = *(const f32x4*)(wr + 4);
      f16x8 a;
      a[0] = (f16)w0[0]; a[1] = (f16)w0[1]; a[2] = (f16)w0[2]; a[3] = (f16)w0[3];
      a[4] = (f16)w1[0]; a[5] = (f16)w1[1]; a[6] = (f16)w1[2]; a[7] = (f16)w1[3];
      afO[cb][ks] = a;
    }
  __syncthreads();
  {
#pragma unroll
    for (int pxb = 0; pxb < 2; pxb++) {
      int pl = wv * 32 + pxb * 16;
      f16x8 bf[2];
#pragma unroll
      for (int ks = 0; ks < 2; ks++)
        bf[ks] = *(const f16x8*)&buf[BIDX(pl + r16, ks * 32 + g4 * 8)];
      f32x4 acc[4];
#pragma unroll
      for (int cb = 0; cb < 4; cb++) acc[cb] = (f32x4){0.f, 0.f, 0.f, 0.f};
#pragma unroll
      for (int cb = 0; cb < 4; cb++)
#pragma unroll
        for (int ks = 0; ks < 2; ks++)
          acc[cb] = __builtin_amdgcn_mfma_f32_16x16x32_f16(afO[cb][ks], bf[ks], acc[cb], 0, 0, 0);
      int px = pl + r16;
      float xv = xs[px];
      float* dst = outp + (size_t)b * 64 * NP + p0 + px;
#pragma unroll
      for (int cb = 0; cb < 4; cb++)
#pragma unroll
        for (int j = 0; j < 4; j++) {
          int d = cb * 16 + g4 * 4 + j;
          dst[(size_t)d * NP] = acc[cb][j] + bD[d] + xv * fcAS[d];
        }
    }
  }
}

extern "C" void kernel_launch(void* const* d_in, const int* in_sizes, int n_in,
                              void* d_out, int out_size, void* d_ws, size_t ws_size,
                              hipStream_t stream) {
  const float* x = (const float*)d_in[0];
  const float* w_in = (const float*)d_in[1];
  const float* b_in = (const float*)d_in[2];
  const float* dw_w[3] = {(const float*)d_in[3], (const float*)d_in[10], (const float*)d_in[17]};
  const float* pw_w[3] = {(const float*)d_in[4], (const float*)d_in[11], (const float*)d_in[18]};
  const float* pw_b[3] = {(const float*)d_in[5], (const float*)d_in[12], (const float*)d_in[19]};
  const float* bng[3] = {(const float*)d_in[6], (const float*)d_in[13], (const float*)d_in[20]};
  const float* bnb[3] = {(const float*)d_in[7], (const float*)d_in[14], (const float*)d_in[21]};
  const float* bnm[3] = {(const float*)d_in[8], (const float*)d_in[15], (const float*)d_in[22]};
  const float* bnv[3] = {(const float*)d_in[9], (const float*)d_in[16], (const float*)d_in[23]};
  const float* imp1_w = (const float*)d_in[24];
  const float* imp1_b = (const float*)d_in[25];
  const float* imp2_w = (const float*)d_in[26];
  const float* imp2_b = (const float*)d_in[27];
  const float* v_w = (const float*)d_in[28];
  const float* v_b = (const float*)d_in[29];
  const float* out_w = (const float*)d_in[30];
  const float* out_b = (const float*)d_in[31];
  const float* fc_w = (const float*)d_in[32];
  const float* fc_b = (const float*)d_in[33];

  char* ws = (char*)d_ws;
  size_t off = 0;
  auto alloc = [&](size_t sz) {
    size_t o = off;
    off = (off + sz + 255) & ~(size_t)255;
    return o;
  };
  float* mbuf = (float*)(ws + alloc((size_t)BB * NP * 4));
  unsigned* ghist = (unsigned*)(ws + alloc((size_t)BB * 2048 * 4));
  unsigned* prefix = (unsigned*)(ws + alloc(8 * 4));
  int* remv = (int*)(ws + alloc(8 * 4));
  unsigned* selT = (unsigned*)(ws + alloc(8 * 4));
  int* selNeed = (int*)(ws + alloc(8 * 4));
  unsigned* cntbuf = (unsigned*)(ws + alloc((size_t)BB * CHUNKS * 4));
  float* fcA = (float*)(ws + alloc(64 * 4));
  float* bDg = (float*)(ws + alloc(64 * 4));
  f16* mx = (f16*)(ws + alloc((size_t)BB * NP * 2));
  f16* mk = (f16*)(ws + alloc((size_t)BB * NP * 2));
  f16* tmp = (f16*)(ws + alloc((size_t)BB * 64 * NP * 2));
  f16* F0 = (f16*)(ws + alloc((size_t)BB * 64 * NP * 2));
  f16* F1 = (f16*)(ws + alloc((size_t)BB * 64 * NP * 2));
  f16* F2 = (f16*)(ws + alloc((size_t)BB * 64 * NP * 2));
  float* kg = (float*)(ws + alloc(512 * 4));

  const int PIX_BLKS = (BB * NP) / 256;              // 1568
  const int DW4_BLKS = (BB * 64 * 56 * 28) / 256;    // 3136
  dim3 tile_grid(NP / 128, BB);                      // 392 x 8
  dim3 chunk_grid(CHUNKS, BB);                       // 196 x 8
  dim3 hist_grid(HB, BB);                            // 28 x 8

  k_m<<<PIX_BLKS, 256, 0, stream>>>(x, w_in, b_in, imp1_w, imp1_b, imp2_w, imp2_b, mbuf);
  k_init<<<64, 256, 0, stream>>>(ghist, prefix, remv);
  k_setup<<<1, 64, 0, stream>>>(w_in, b_in, out_b, fc_w, fc_b, fcA, bDg);
  // 3-pass radix select: 11 + 11 + 10 bits
  k_hist<21, 0u, 2048><<<hist_grid, 256, 0, stream>>>(mbuf, prefix, ghist);
  k_pick<21, 2048, 0><<<BB, 256, 0, stream>>>(ghist, prefix, remv, selT, selNeed);
  k_hist<10, 0xFFE00000u, 2048><<<hist_grid, 256, 0, stream>>>(mbuf, prefix, ghist);
  k_pick<10, 2048, 0><<<BB, 256, 0, stream>>>(ghist, prefix, remv, selT, selNeed);
  k_hist<0, 0xFFFFFC00u, 1024><<<hist_grid, 256, 0, stream>>>(mbuf, prefix, ghist);
  k_pick<0, 1024, 1><<<BB, 256, 0, stream>>>(ghist, prefix, remv, selT, selNeed);

  k_cnteq<<<chunk_grid, 256, 0, stream>>>(mbuf, selT, cntbuf);
  k_scan<<<BB, 256, 0, stream>>>(cntbuf);
  k_maskw<<<chunk_grid, 256, 0, stream>>>(mbuf, x, selT, selNeed, cntbuf, mx, mk);

  // level 0
  k_dw0<<<DW4_BLKS, 256, 0, stream>>>(dw_w[0], w_in, b_in, mx, mk, tmp);
  k_pwm<<<tile_grid, 256, 0, stream>>>(tmp, pw_w[0], pw_b[0], bng[0], bnb[0], bnm[0], bnv[0], F0);
  // level 1
  k_dw4<5, 2><<<DW4_BLKS, 256, 0, stream>>>(dw_w[1], F0, tmp);
  k_pwm<<<tile_grid, 256, 0, stream>>>(tmp, pw_w[1], pw_b[1], bng[1], bnb[1], bnm[1], bnv[1], F1);
  // level 2
  k_dw4<7, 4><<<DW4_BLKS, 256, 0, stream>>>(dw_w[2], F1, tmp);
  k_pwm<<<tile_grid, 256, 0, stream>>>(tmp, pw_w[2], pw_b[2], bng[2], bnb[2], bnm[2], bnv[2], F2);

  k_mean<<<512, 256, 0, stream>>>(F2, kg);
  k_final<<<tile_grid, 256, 0, stream>>>(x, w_in, b_in, F0, F1, F2, kg, fcA, bDg,
                                         v_w, v_b, out_w, (float*)d_out);
}

// Round 17
// 369.968 us; speedup vs baseline: 1.2687x; 1.1213x over previous
//
#include <hip/hip_runtime.h>
#include <hip/hip_fp16.h>

typedef _Float16 f16;
typedef _Float16 f16x8 __attribute__((ext_vector_type(8)));
typedef _Float16 f16x4 __attribute__((ext_vector_type(4)));
typedef float f32x4 __attribute__((ext_vector_type(4)));

static constexpr int BB = 8, HH = 224, WW = 224, NP = HH * WW; // 50176
static constexpr int TOPK = 15052;  // max(int(0.3*224*224), 64)
static constexpr int LDR = 72;      // LDS row stride (f16)
static constexpr int CHUNKS = NP / 256;  // 196
static constexpr int HB = 28;       // hist blocks per batch; NP/HB = 1792

// XOR-swizzled LDS index for buf (fixes px8-strided scalar-write 16-way conflict).
__device__ __forceinline__ int BIDX(int px, int ci) {
  return px * LDR + (ci ^ (((px >> 3) & 7) << 3));
}

// ---------------- K2 (fused): m = sigmoid(conv3x3(relu(A_j x + B_j)) + b)
__global__ __launch_bounds__(256) void k_m(const float* __restrict__ x,
    const float* __restrict__ w_in, const float* __restrict__ b_in,
    const float* __restrict__ imp1_w, const float* __restrict__ imp1_b,
    const float* __restrict__ imp2_w, const float* __restrict__ imp2_b,
    float* __restrict__ m) {
  __shared__ float A[16], Bv[16], w2[144];
  __shared__ float bsh;
  int t = threadIdx.x;
  if (t < 144) w2[t] = imp2_w[t];
  if (t == 0) bsh = imp2_b[0];
  if (t < 16) {
    float a = 0.f, bb = 0.f;
    for (int c = 0; c < 64; c++) {
      float iw = imp1_w[t * 64 + c];
      a = fmaf(iw, w_in[64 + c], a);
      bb = fmaf(iw, b_in[64 + c], bb);
    }
    A[t] = a;
    Bv[t] = bb + imp1_b[t];
  }
  __syncthreads();
  int p = blockIdx.x * 256 + t;
  int b = p / NP, pp = p - b * NP;
  int h = pp / WW, w = pp - h * WW;
  const float* xb = x + (size_t)b * NP;
  float s = bsh;
#pragma unroll
  for (int ky = 0; ky < 3; ky++) {
    int hy = h + ky - 1;
    if ((unsigned)hy >= (unsigned)HH) continue;
#pragma unroll
    for (int kx = 0; kx < 3; kx++) {
      int wx = w + kx - 1;
      if ((unsigned)wx >= (unsigned)WW) continue;
      float xn = xb[hy * WW + wx];
#pragma unroll
      for (int j = 0; j < 16; j++) {
        float m1 = fmaxf(fmaf(A[j], xn, Bv[j]), 0.f);
        s = fmaf(w2[j * 9 + ky * 3 + kx], m1, s);
      }
    }
  }
  m[p] = 1.f / (1.f + expf(-s));
}

// ---------------- K_setup: block-invariant epilogue constants
__global__ __launch_bounds__(64) void k_setup(const float* __restrict__ w_in,
    const float* __restrict__ b_in, const float* __restrict__ out_b,
    const float* __restrict__ fc_w, const float* __restrict__ fc_b,
    float* __restrict__ fcA, float* __restrict__ bDg) {
  int d = threadIdx.x;
  float fa = 0.f, fb = 0.f;
  for (int c = 0; c < 64; c++) {
    float fw = fc_w[d * 64 + c];
    fa = fmaf(fw, w_in[c], fa);
    fb = fmaf(fw, b_in[c], fb);
  }
  fcA[d] = fa;
  bDg[d] = out_b[d] + fc_b[d] + fb;
}

// ---------------- K_cvtw: pre-convert the five 64x64 weight matrices to f16
__global__ __launch_bounds__(256) void k_cvtw(const float* __restrict__ a0,
    const float* __restrict__ a1, const float* __restrict__ a2,
    const float* __restrict__ a3, const float* __restrict__ a4,
    f16* __restrict__ dst) {
  int mtx = blockIdx.x;
  const float* s = (mtx == 0) ? a0 : (mtx == 1) ? a1 : (mtx == 2) ? a2 : (mtx == 3) ? a3 : a4;
  int t = threadIdx.x;
  for (int i = t; i < 4096; i += 256) dst[mtx * 4096 + i] = (f16)s[i];
}

// ---------------- K3a: init select state
__global__ __launch_bounds__(256) void k_init(unsigned* __restrict__ ghist,
    unsigned* __restrict__ prefix, int* __restrict__ rem) {
  int i = blockIdx.x * 256 + threadIdx.x;
  if (i < 8 * 2048) ghist[i] = 0u;
  if (i < 8) { prefix[i] = 0u; rem[i] = TOPK; }
}

// ---------------- K3b: grid-parallel histogram of one radix digit
template <int SHIFT, unsigned HIMASK, int BINS>
__global__ __launch_bounds__(256) void k_hist(const float* __restrict__ m,
    const unsigned* __restrict__ prefix, unsigned* __restrict__ ghist) {
  __shared__ unsigned hist[2048];
  int b = blockIdx.y, blk = blockIdx.x, t = threadIdx.x;
  for (int i = t; i < BINS; i += 256) hist[i] = 0u;
  __syncthreads();
  unsigned pfx = prefix[b];
  const float* mb = m + (size_t)b * NP + blk * (NP / HB);
#pragma unroll
  for (int it = 0; it < NP / HB / 256; it++) {
    unsigned bits = __float_as_uint(mb[it * 256 + t]);
    if ((bits & HIMASK) == pfx) atomicAdd(&hist[(bits >> SHIFT) & (BINS - 1)], 1u);
  }
  __syncthreads();
  unsigned* gh = ghist + b * 2048;
  for (int i = t; i < BINS; i += 256) {
    unsigned v = hist[i];
    if (v) atomicAdd(&gh[i], v);
  }
}

// ---------------- K3c: pick k-th bin via suffix scan; advance prefix/rem; zero ghist
template <int SHIFT, int BINS, int FINAL>
__global__ __launch_bounds__(256) void k_pick(unsigned* __restrict__ ghist,
    unsigned* __restrict__ prefix, int* __restrict__ rem,
    unsigned* __restrict__ selT, int* __restrict__ selNeed) {
  __shared__ unsigned s[256];
  int b = blockIdx.x, t = threadIdx.x;
  constexpr int PER = BINS / 256;
  unsigned* gh = ghist + b * 2048;
  unsigned local[PER];
  unsigned sum = 0;
#pragma unroll
  for (int j = 0; j < PER; j++) { local[j] = gh[t * PER + j]; sum += local[j]; }
#pragma unroll
  for (int j = 0; j < PER; j++) gh[t * PER + j] = 0u;
  s[t] = sum;
  int rm = rem[b];
  unsigned pfx = prefix[b];
  __syncthreads();
  for (int o = 1; o < 256; o <<= 1) {
    unsigned v = (t + o < 256) ? s[t + o] : 0u;
    __syncthreads();
    s[t] += v;
    __syncthreads();
  }
  unsigned nb = (t < 255) ? s[t + 1] : 0u;
  if (s[t] >= (unsigned)rm && nb < (unsigned)rm) {
    int acc = (int)nb;
#pragma unroll
    for (int j = PER - 1; j >= 0; j--) {
      acc += (int)local[j];
      if (acc >= rm) {
        unsigned bin = (unsigned)(t * PER + j);
        int need = rm - (acc - (int)local[j]);
        if (FINAL) {
          selT[b] = pfx | (bin << SHIFT);
          selNeed[b] = need;
        } else {
          prefix[b] = pfx | (bin << SHIFT);
          rem[b] = need;
        }
        break;
      }
    }
  }
}

// ---------------- K4a: per-chunk count of (bits == T)
__global__ __launch_bounds__(256) void k_cnteq(const float* __restrict__ m,
    const unsigned* __restrict__ selT, unsigned* __restrict__ cnt) {
  int b = blockIdx.y, ch = blockIdx.x, t = threadIdx.x;
  unsigned T = selT[b];
  unsigned bits = __float_as_uint(m[(size_t)b * NP + ch * 256 + t]);
  unsigned long long em = __ballot(bits == T);
  __shared__ unsigned wc[4];
  if ((t & 63) == 0) wc[t >> 6] = (unsigned)__popcll(em);
  __syncthreads();
  if (t == 0) cnt[b * CHUNKS + ch] = wc[0] + wc[1] + wc[2] + wc[3];
}

// ---------------- K4b: per-batch exclusive scan of chunk counts
__global__ __launch_bounds__(256) void k_scan(unsigned* __restrict__ cnt) {
  __shared__ unsigned s[256];
  int b = blockIdx.x, t = threadIdx.x;
  unsigned v = (t < CHUNKS) ? cnt[b * CHUNKS + t] : 0u;
  s[t] = v;
  __syncthreads();
  for (int o = 1; o < 256; o <<= 1) {
    unsigned u = (t >= o) ? s[t - o] : 0u;
    __syncthreads();
    s[t] += u;
    __syncthreads();
  }
  if (t < CHUNKS) cnt[b * CHUNKS + t] = s[t] - v;
}

// ---------------- K4c: stable mask write (ties by ascending index)
__global__ __launch_bounds__(256) void k_maskw(const float* __restrict__ m,
    const float* __restrict__ x,
    const unsigned* __restrict__ selT, const int* __restrict__ selNeed,
    const unsigned* __restrict__ cnt,
    f16* __restrict__ mx, f16* __restrict__ mk) {
  int b = blockIdx.y, ch = blockIdx.x, t = threadIdx.x;
  int lane = t & 63, wv = t >> 6;
  unsigned T = selT[b];
  int need = selNeed[b];
  size_t i = (size_t)b * NP + ch * 256 + t;
  unsigned bits = __float_as_uint(m[i]);
  bool gt = bits > T, eq = bits == T;
  unsigned long long em = __ballot(eq);
  __shared__ unsigned wc[4];
  if (lane == 0) wc[wv] = (unsigned)__popcll(em);
  __syncthreads();
  int base = (int)cnt[b * CHUNKS + ch];
  for (int w = 0; w < wv; w++) base += (int)wc[w];
  int rank = (int)__popcll(em & ((1ULL << lane) - 1ULL));
  bool sel = gt || (eq && (base + rank) < need);
  mk[i] = sel ? (f16)1.f : (f16)0.f;
  mx[i] = sel ? (f16)x[i] : (f16)0.f;
}

// ---------------- K5a: 4-row-grouped depthwise lvl0, weights in VGPRs, m unrolled
__global__ __launch_bounds__(256) void k_dw0(const float* __restrict__ dw_w,
    const float* __restrict__ w_in, const float* __restrict__ b_in,
    const f16* __restrict__ mx, const f16* __restrict__ mk,
    f16* __restrict__ outp) {
  constexpr int LOFF = 8, NLD = 3;
  int g = blockIdx.x * 256 + threadIdx.x;
  int w8 = g % 28;
  int rem = g / 28;
  int rowg = rem % 56, bc = rem / 56;
  int b = bc >> 6, c = bc & 63;
  int w0 = w8 * 8;
  int h0 = rowg * 4;
  const f16* mxb = mx + (size_t)b * NP;
  const f16* mkb = mk + (size_t)b * NP;
  float kw = w_in[64 + c], kb = b_in[64 + c];
  const float* wp = dw_w + c * 9;
  float wa[9], wb[9];
#pragma unroll
  for (int i = 0; i < 9; i++) {
    float wv = wp[i];
    wa[i] = wv * kw;
    wb[i] = wv * kb;
  }
  float acc[4][8] = {};
#pragma unroll
  for (int m = 0; m < 6; m++) {
    int him = h0 + m - 1;
    if ((unsigned)him >= (unsigned)HH) continue;
    float rx[NLD * 8], rk[NLD * 8];
    const f16* rpx = mxb + him * WW + (w0 - LOFF);
    const f16* rpk = mkb + him * WW + (w0 - LOFF);
#pragma unroll
    for (int s = 0; s < NLD; s++) {
      int ws_ = w0 - LOFF + s * 8;
      if ((unsigned)ws_ < (unsigned)WW) {
        f16x8 vx = *(const f16x8*)(rpx + s * 8);
        f16x8 vk = *(const f16x8*)(rpk + s * 8);
#pragma unroll
        for (int j = 0; j < 8; j++) { rx[s * 8 + j] = (float)vx[j]; rk[s * 8 + j] = (float)vk[j]; }
      } else {
#pragma unroll
        for (int j = 0; j < 8; j++) { rx[s * 8 + j] = 0.f; rk[s * 8 + j] = 0.f; }
      }
    }
#pragma unroll
    for (int j = 0; j < 4; j++) {
      constexpr unsigned K3 = 3u;
      int k = m - j;
      if ((unsigned)k >= K3) continue;
#pragma unroll
      for (int kx = 0; kx < 3; kx++) {
        float a_ = wa[k * 3 + kx], b_ = wb[k * 3 + kx];
#pragma unroll
        for (int p = 0; p < 8; p++) {
          int idx = p + LOFF + (kx - 1);
          acc[j][p] = fmaf(a_, rx[idx], fmaf(b_, rk[idx], acc[j][p]));
        }
      }
    }
  }
#pragma unroll
  for (int j = 0; j < 4; j++) {
    f16x8 o;
#pragma unroll
    for (int p = 0; p < 8; p++) o[p] = (f16)acc[j][p];
    *(f16x8*)(outp + (size_t)bc * NP + (h0 + j) * WW + w0) = o;
  }
}

// ---------------- K5b: 4-row-grouped depthwise lvl1/2, weights in VGPRs, m unrolled
template <int KSZ, int DIL>
__global__ __launch_bounds__(256) void k_dw4(const float* __restrict__ dw_w,
    const f16* __restrict__ fin, f16* __restrict__ outp) {
  constexpr int PAD = (KSZ / 2) * DIL;
  constexpr int LOFF = (PAD + 7) & ~7;
  constexpr int NLD = (LOFF + 8 + PAD + 7) / 8;
  constexpr int NR = KSZ + 3;
  int g = blockIdx.x * 256 + threadIdx.x;
  int w8 = g % 28;
  int rem = g / 28;
  int rowg = rem % 56, bc = rem / 56;
  int w0 = w8 * 8;
  int res = rowg % DIL, grp = rowg / DIL;
  int h0 = res + DIL * 4 * grp;
  int c = bc & 63;
  const f16* fb = fin + (size_t)bc * NP;
  const float* wp = dw_w + c * KSZ * KSZ;
  float wr[KSZ * KSZ];
#pragma unroll
  for (int i = 0; i < KSZ * KSZ; i++) wr[i] = wp[i];
  float acc[4][8] = {};
#pragma unroll
  for (int m = 0; m < NR; m++) {
    int him = h0 + (m - KSZ / 2) * DIL;
    if ((unsigned)him >= (unsigned)HH) continue;
    float r[NLD * 8];
    const f16* rp = fb + him * WW + (w0 - LOFF);
#pragma unroll
    for (int s = 0; s < NLD; s++) {
      int ws_ = w0 - LOFF + s * 8;
      if ((unsigned)ws_ < (unsigned)WW) {
        f16x8 v = *(const f16x8*)(rp + s * 8);
#pragma unroll
        for (int j = 0; j < 8; j++) r[s * 8 + j] = (float)v[j];
      } else {
#pragma unroll
        for (int j = 0; j < 8; j++) r[s * 8 + j] = 0.f;
      }
    }
#pragma unroll
    for (int j = 0; j < 4; j++) {
      int k = m - j;
      if (k < 0 || k >= KSZ) continue;
#pragma unroll
      for (int kx = 0; kx < KSZ; kx++) {
        float wv = wr[k * KSZ + kx];
#pragma unroll
        for (int p = 0; p < 8; p++)
          acc[j][p] = fmaf(wv, r[p + LOFF + (kx - KSZ / 2) * DIL], acc[j][p]);
      }
    }
  }
#pragma unroll
  for (int j = 0; j < 4; j++) {
    f16x8 o;
#pragma unroll
    for (int p = 0; p < 8; p++) o[p] = (f16)acc[j][p];
    *(f16x8*)(outp + (size_t)bc * NP + (h0 + DIL * j) * WW + w0) = o;
  }
}

// ---------------- K6: MFMA pointwise 64x64 + folded BN + relu (f16 weights)
__global__ __launch_bounds__(256) void k_pwm(const f16* __restrict__ inp,
    const f16* __restrict__ pwf, const float* __restrict__ pw_b,
    const float* __restrict__ g, const float* __restrict__ be,
    const float* __restrict__ mu, const float* __restrict__ var,
    f16* __restrict__ outp) {
  __shared__ f16 buf[128 * LDR];
  __shared__ float sc[64], sh[64];
  int t = threadIdx.x;
  if (t < 64) {
    float s = g[t] / sqrtf(var[t] + 1e-5f);
    sc[t] = s;
    sh[t] = (pw_b[t] - mu[t]) * s + be[t];
  }
  int b = blockIdx.y;
  int p0 = blockIdx.x * 128;
  const f16* src = inp + (size_t)b * 64 * NP + p0;
  f16x8 vv[4];
  int cis[4], pxs[4];
#pragma unroll
  for (int it = 0; it < 4; it++) {
    int cidx = it * 256 + t;
    cis[it] = cidx >> 4;
    pxs[it] = (cidx & 15) * 8;
    vv[it] = *(const f16x8*)(src + (size_t)cis[it] * NP + pxs[it]);
  }
#pragma unroll
  for (int it = 0; it < 4; it++) {
#pragma unroll
    for (int j = 0; j < 8; j++) buf[BIDX(pxs[it] + j, cis[it])] = vv[it][j];
  }
  __syncthreads();
  int ln = t & 63, wv = t >> 6;
  int r16 = ln & 15, g4 = ln >> 4;
  f16x8 af[4][2];
#pragma unroll
  for (int cb = 0; cb < 4; cb++)
#pragma unroll
    for (int ks = 0; ks < 2; ks++)
      af[cb][ks] = *(const f16x8*)(pwf + (cb * 16 + r16) * 64 + ks * 32 + g4 * 8);
#pragma unroll
  for (int pxb = 0; pxb < 2; pxb++) {
    int pl = wv * 32 + pxb * 16;
    f16x8 bf[2];
#pragma unroll
    for (int ks = 0; ks < 2; ks++)
      bf[ks] = *(const f16x8*)&buf[BIDX(pl + r16, ks * 32 + g4 * 8)];
    f32x4 acc[4];
#pragma unroll
    for (int cb = 0; cb < 4; cb++) acc[cb] = (f32x4){0.f, 0.f, 0.f, 0.f};
#pragma unroll
    for (int cb = 0; cb < 4; cb++)
#pragma unroll
      for (int ks = 0; ks < 2; ks++)
        acc[cb] = __builtin_amdgcn_mfma_f32_16x16x32_f16(af[cb][ks], bf[ks], acc[cb], 0, 0, 0);
    f16* dst = outp + (size_t)b * 64 * NP + p0 + pl + r16;
#pragma unroll
    for (int cb = 0; cb < 4; cb++)
#pragma unroll
      for (int j = 0; j < 4; j++) {
        int co = cb * 16 + g4 * 4 + j;
        float o = fmaf(acc[cb][j], sc[co], sh[co]);
        dst[(size_t)co * NP] = (f16)fmaxf(o, 0.f);
      }
  }
}

// ---------------- K7: K_global = mean over pixels of focal[2]
__global__ __launch_bounds__(256) void k_mean(const f16* __restrict__ F2,
                                              float* __restrict__ kg) {
  int bc = blockIdx.x;
  const f16* f = F2 + (size_t)bc * NP;
  float s = 0.f;
  for (int i = threadIdx.x; i < NP; i += 256) s += (float)f[i];
  __shared__ float r[256];
  r[threadIdx.x] = s;
  __syncthreads();
  for (int o = 128; o > 0; o >>= 1) {
    if (threadIdx.x < o) r[threadIdx.x] += r[threadIdx.x + o];
    __syncthreads();
  }
  if (threadIdx.x == 0) kg[bc] = r[0] * (1.f / NP);
}

// ---------------- K8: fused K_final -> V -> QV -> out (f16 weights)
__global__ __launch_bounds__(256) void k_final(const float* __restrict__ x,
    const float* __restrict__ w_in, const float* __restrict__ b_in,
    const f16* __restrict__ F0, const f16* __restrict__ F1, const f16* __restrict__ F2,
    const float* __restrict__ kg, const float* __restrict__ fcA,
    const float* __restrict__ bDg,
    const f16* __restrict__ vwf, const float* __restrict__ v_b,
    const f16* __restrict__ owf,
    float* __restrict__ outp) {
  __shared__ f16 buf[128 * LDR];
  __shared__ float gvs[128 * 4];  // row r = gv for px = IROT(r)
  __shared__ float xs[128];
  __shared__ float kgs[64], qwS[64], qbS[64], vbS[64], bD[64], fcAS[64];
  int t = threadIdx.x;
  int b = blockIdx.y;
  int p0 = blockIdx.x * 128;
  if (t < 64) {
    kgs[t] = kg[b * 64 + t];
    qwS[t] = w_in[t];
    qbS[t] = b_in[t];
    vbS[t] = v_b[t];
    fcAS[t] = fcA[t];
    bD[t] = bDg[t];
  }
  if (t < 128) {
    int px = ((t & 15) << 3) | (t >> 4);  // IROT(t)
    float xv = x[(size_t)b * NP + p0 + px];
    xs[px] = xv;
    float gv[4], mxv = -1e30f;
#pragma unroll
    for (int j = 0; j < 4; j++) {
      gv[j] = fmaf(xv, w_in[128 + j], b_in[128 + j]);
      mxv = fmaxf(mxv, gv[j]);
    }
    float se = 0.f;
#pragma unroll
    for (int j = 0; j < 4; j++) { gv[j] = expf(gv[j] - mxv); se += gv[j]; }
    float inv = 1.f / se;
    f32x4 g4v;
#pragma unroll
    for (int j = 0; j < 4; j++) g4v[j] = gv[j] * inv;
    *(f32x4*)&gvs[t * 4] = g4v;
  }
  const f16* f0 = F0 + (size_t)b * 64 * NP + p0;
  const f16* f1 = F1 + (size_t)b * 64 * NP + p0;
  const f16* f2 = F2 + (size_t)b * 64 * NP + p0;
  f16x8 s0[4], s1[4], s2[4];
  int cis[4], pxs[4];
#pragma unroll
  for (int it = 0; it < 4; it++) {
    int cidx = it * 256 + t;
    cis[it] = cidx >> 4;
    pxs[it] = (cidx & 15) * 8;
    size_t o = (size_t)cis[it] * NP + pxs[it];
    s0[it] = *(const f16x8*)(f0 + o);
    s1[it] = *(const f16x8*)(f1 + o);
    s2[it] = *(const f16x8*)(f2 + o);
  }
  int ln = t & 63, wv = t >> 6;
  int r16 = ln & 15, g4 = ln >> 4;
  f16x8 afV[4][2];
#pragma unroll
  for (int cb = 0; cb < 4; cb++)
#pragma unroll
    for (int ks = 0; ks < 2; ks++)
      afV[cb][ks] = *(const f16x8*)(vwf + (cb * 16 + r16) * 64 + ks * 32 + g4 * 8);
  __syncthreads();
#pragma unroll
  for (int it = 0; it < 4; it++) {
    int ci = cis[it], px8 = pxs[it];
    float kgc = kgs[ci];
#pragma unroll
    for (int j = 0; j < 8; j++) {
      int px = px8 + j;
      f32x4 gv = *(const f32x4*)&gvs[(((px & 7) << 4) | (px >> 3)) * 4];
      float kf = gv[0] * (float)s0[it][j] + gv[1] * (float)s1[it][j] +
                 gv[2] * (float)s2[it][j] + gv[3] * kgc;
      buf[BIDX(px, ci)] = (f16)kf;
    }
  }
  __syncthreads();
  {
#pragma unroll
    for (int pxb = 0; pxb < 2; pxb++) {
      int pl = wv * 32 + pxb * 16;
      f16x8 bf[2];
#pragma unroll
      for (int ks = 0; ks < 2; ks++)
        bf[ks] = *(const f16x8*)&buf[BIDX(pl + r16, ks * 32 + g4 * 8)];
      f32x4 acc[4];
#pragma unroll
      for (int cb = 0; cb < 4; cb++) acc[cb] = (f32x4){0.f, 0.f, 0.f, 0.f};
#pragma unroll
      for (int cb = 0; cb < 4; cb++)
#pragma unroll
        for (int ks = 0; ks < 2; ks++)
          acc[cb] = __builtin_amdgcn_mfma_f32_16x16x32_f16(afV[cb][ks], bf[ks], acc[cb], 0, 0, 0);
      int px = pl + r16;
      float xv = xs[px];
#pragma unroll
      for (int cb = 0; cb < 4; cb++) {
        f16x4 q4;
#pragma unroll
        for (int j = 0; j < 4; j++) {
          int co = cb * 16 + g4 * 4 + j;
          float V = acc[cb][j] + vbS[co];
          float q = fmaf(xv, qwS[co], qbS[co]);
          q4[j] = (f16)(q * V);
        }
        *(f16x4*)&buf[BIDX(px, cb * 16 + g4 * 4)] = q4;
      }
    }
  }
  f16x8 afO[4][2];
#pragma unroll
  for (int cb = 0; cb < 4; cb++)
#pragma unroll
    for (int ks = 0; ks < 2; ks++)
      afO[cb][ks] = *(const f16x8*)(owf + (cb * 16 + r16) * 64 + ks * 32 + g4 * 8);
  __syncthreads();
  {
#pragma unroll
    for (int pxb = 0; pxb < 2; pxb++) {
      int pl = wv * 32 + pxb * 16;
      f16x8 bf[2];
#pragma unroll
      for (int ks = 0; ks < 2; ks++)
        bf[ks] = *(const f16x8*)&buf[BIDX(pl + r16, ks * 32 + g4 * 8)];
      f32x4 acc[4];
#pragma unroll
      for (int cb = 0; cb < 4; cb++) acc[cb] = (f32x4){0.f, 0.f, 0.f, 0.f};
#pragma unroll
      for (int cb = 0; cb < 4; cb++)
#pragma unroll
        for (int ks = 0; ks < 2; ks++)
          acc[cb] = __builtin_amdgcn_mfma_f32_16x16x32_f16(afO[cb][ks], bf[ks], acc[cb], 0, 0, 0);
      int px = pl + r16;
      float xv = xs[px];
      float* dst = outp + (size_t)b * 64 * NP + p0 + px;
#pragma unroll
      for (int cb = 0; cb < 4; cb++)
#pragma unroll
        for (int j = 0; j < 4; j++) {
          int d = cb * 16 + g4 * 4 + j;
          dst[(size_t)d * NP] = acc[cb][j] + bD[d] + xv * fcAS[d];
        }
    }
  }
}

extern "C" void kernel_launch(void* const* d_in, const int* in_sizes, int n_in,
                              void* d_out, int out_size, void* d_ws, size_t ws_size,
                              hipStream_t stream) {
  const float* x = (const float*)d_in[0];
  const float* w_in = (const float*)d_in[1];
  const float* b_in = (const float*)d_in[2];
  const float* dw_w[3] = {(const float*)d_in[3], (const float*)d_in[10], (const float*)d_in[17]};
  const float* pw_w[3] = {(const float*)d_in[4], (const float*)d_in[11], (const float*)d_in[18]};
  const float* pw_b[3] = {(const float*)d_in[5], (const float*)d_in[12], (const float*)d_in[19]};
  const float* bng[3] = {(const float*)d_in[6], (const float*)d_in[13], (const float*)d_in[20]};
  const float* bnb[3] = {(const float*)d_in[7], (const float*)d_in[14], (const float*)d_in[21]};
  const float* bnm[3] = {(const float*)d_in[8], (const float*)d_in[15], (const float*)d_in[22]};
  const float* bnv[3] = {(const float*)d_in[9], (const float*)d_in[16], (const float*)d_in[23]};
  const float* imp1_w = (const float*)d_in[24];
  const float* imp1_b = (const float*)d_in[25];
  const float* imp2_w = (const float*)d_in[26];
  const float* imp2_b = (const float*)d_in[27];
  const float* v_w = (const float*)d_in[28];
  const float* v_b = (const float*)d_in[29];
  const float* out_w = (const float*)d_in[30];
  const float* out_b = (const float*)d_in[31];
  const float* fc_w = (const float*)d_in[32];
  const float* fc_b = (const float*)d_in[33];

  char* ws = (char*)d_ws;
  size_t off = 0;
  auto alloc = [&](size_t sz) {
    size_t o = off;
    off = (off + sz + 255) & ~(size_t)255;
    return o;
  };
  float* mbuf = (float*)(ws + alloc((size_t)BB * NP * 4));
  unsigned* ghist = (unsigned*)(ws + alloc((size_t)BB * 2048 * 4));
  unsigned* prefix = (unsigned*)(ws + alloc(8 * 4));
  int* remv = (int*)(ws + alloc(8 * 4));
  unsigned* selT = (unsigned*)(ws + alloc(8 * 4));
  int* selNeed = (int*)(ws + alloc(8 * 4));
  unsigned* cntbuf = (unsigned*)(ws + alloc((size_t)BB * CHUNKS * 4));
  float* fcA = (float*)(ws + alloc(64 * 4));
  float* bDg = (float*)(ws + alloc(64 * 4));
  f16* wf = (f16*)(ws + alloc((size_t)5 * 4096 * 2));  // pw0,pw1,pw2,v_w,out_w (f16)
  f16* mx = (f16*)(ws + alloc((size_t)BB * NP * 2));
  f16* mk = (f16*)(ws + alloc((size_t)BB * NP * 2));
  f16* tmp = (f16*)(ws + alloc((size_t)BB * 64 * NP * 2));
  f16* F0 = (f16*)(ws + alloc((size_t)BB * 64 * NP * 2));
  f16* F1 = (f16*)(ws + alloc((size_t)BB * 64 * NP * 2));
  f16* F2 = (f16*)(ws + alloc((size_t)BB * 64 * NP * 2));
  float* kg = (float*)(ws + alloc(512 * 4));

  const int PIX_BLKS = (BB * NP) / 256;              // 1568
  const int DW4_BLKS = (BB * 64 * 56 * 28) / 256;    // 3136
  dim3 tile_grid(NP / 128, BB);                      // 392 x 8
  dim3 chunk_grid(CHUNKS, BB);                       // 196 x 8
  dim3 hist_grid(HB, BB);                            // 28 x 8

  k_m<<<PIX_BLKS, 256, 0, stream>>>(x, w_in, b_in, imp1_w, imp1_b, imp2_w, imp2_b, mbuf);
  k_init<<<64, 256, 0, stream>>>(ghist, prefix, remv);
  k_setup<<<1, 64, 0, stream>>>(w_in, b_in, out_b, fc_w, fc_b, fcA, bDg);
  k_cvtw<<<5, 256, 0, stream>>>(pw_w[0], pw_w[1], pw_w[2], v_w, out_w, wf);
  // 3-pass radix select: 11 + 11 + 10 bits
  k_hist<21, 0u, 2048><<<hist_grid, 256, 0, stream>>>(mbuf, prefix, ghist);
  k_pick<21, 2048, 0><<<BB, 256, 0, stream>>>(ghist, prefix, remv, selT, selNeed);
  k_hist<10, 0xFFE00000u, 2048><<<hist_grid, 256, 0, stream>>>(mbuf, prefix, ghist);
  k_pick<10, 2048, 0><<<BB, 256, 0, stream>>>(ghist, prefix, remv, selT, selNeed);
  k_hist<0, 0xFFFFFC00u, 1024><<<hist_grid, 256, 0, stream>>>(mbuf, prefix, ghist);
  k_pick<0, 1024, 1><<<BB, 256, 0, stream>>>(ghist, prefix, remv, selT, selNeed);

  k_cnteq<<<chunk_grid, 256, 0, stream>>>(mbuf, selT, cntbuf);
  k_scan<<<BB, 256, 0, stream>>>(cntbuf);
  k_maskw<<<chunk_grid, 256, 0, stream>>>(mbuf, x, selT, selNeed, cntbuf, mx, mk);

  // level 0
  k_dw0<<<DW4_BLKS, 256, 0, stream>>>(dw_w[0], w_in, b_in, mx, mk, tmp);
  k_pwm<<<tile_grid, 256, 0, stream>>>(tmp, wf + 0 * 4096, pw_b[0], bng[0], bnb[0], bnm[0], bnv[0], F0);
  // level 1
  k_dw4<5, 2><<<DW4_BLKS, 256, 0, stream>>>(dw_w[1], F0, tmp);
  k_pwm<<<tile_grid, 256, 0, stream>>>(tmp, wf + 1 * 4096, pw_b[1], bng[1], bnb[1], bnm[1], bnv[1], F1);
  // level 2
  k_dw4<7, 4><<<DW4_BLKS, 256, 0, stream>>>(dw_w[2], F1, tmp);
  k_pwm<<<tile_grid, 256, 0, stream>>>(tmp, wf + 2 * 4096, pw_b[2], bng[2], bnb[2], bnm[2], bnv[2], F2);

  k_mean<<<512, 256, 0, stream>>>(F2, kg);
  k_final<<<tile_grid, 256, 0, stream>>>(x, w_in, b_in, F0, F1, F2, kg, fcA, bDg,
                                         wf + 3 * 4096, v_b, wf + 4 * 4096, (float*)d_out);
}

// Round 18
// 369.675 us; speedup vs baseline: 1.2697x; 1.0008x over previous
//
#include <hip/hip_runtime.h>
#include <hip/hip_fp16.h>

typedef _Float16 f16;
typedef _Float16 f16x8 __attribute__((ext_vector_type(8)));
typedef _Float16 f16x4 __attribute__((ext_vector_type(4)));
typedef float f32x4 __attribute__((ext_vector_type(4)));
typedef float f32x2 __attribute__((ext_vector_type(2)));

static constexpr int BB = 8, HH = 224, WW = 224, NP = HH * WW; // 50176
static constexpr int TOPK = 15052;  // max(int(0.3*224*224), 64)
static constexpr int LDR = 72;      // LDS row stride (f16)
static constexpr int CHUNKS = NP / 256;  // 196
static constexpr int HB = 28;       // hist blocks per batch; NP/HB = 1792

// XOR-swizzled LDS index for buf (fixes px8-strided scalar-write 16-way conflict).
__device__ __forceinline__ int BIDX(int px, int ci) {
  return px * LDR + (ci ^ (((px >> 3) & 7) << 3));
}

// ---------------- K2 (fused): m = sigmoid(conv3x3(relu(A_j x + B_j)) + b)
__global__ __launch_bounds__(256) void k_m(const float* __restrict__ x,
    const float* __restrict__ w_in, const float* __restrict__ b_in,
    const float* __restrict__ imp1_w, const float* __restrict__ imp1_b,
    const float* __restrict__ imp2_w, const float* __restrict__ imp2_b,
    float* __restrict__ m) {
  __shared__ float A[16], Bv[16], w2[144];
  __shared__ float bsh;
  int t = threadIdx.x;
  if (t < 144) w2[t] = imp2_w[t];
  if (t == 0) bsh = imp2_b[0];
  if (t < 16) {
    float a = 0.f, bb = 0.f;
    for (int c = 0; c < 64; c++) {
      float iw = imp1_w[t * 64 + c];
      a = fmaf(iw, w_in[64 + c], a);
      bb = fmaf(iw, b_in[64 + c], bb);
    }
    A[t] = a;
    Bv[t] = bb + imp1_b[t];
  }
  __syncthreads();
  int p = blockIdx.x * 256 + t;
  int b = p / NP, pp = p - b * NP;
  int h = pp / WW, w = pp - h * WW;
  const float* xb = x + (size_t)b * NP;
  float s = bsh;
#pragma unroll
  for (int ky = 0; ky < 3; ky++) {
    int hy = h + ky - 1;
    if ((unsigned)hy >= (unsigned)HH) continue;
#pragma unroll
    for (int kx = 0; kx < 3; kx++) {
      int wx = w + kx - 1;
      if ((unsigned)wx >= (unsigned)WW) continue;
      float xn = xb[hy * WW + wx];
#pragma unroll
      for (int j = 0; j < 16; j++) {
        float m1 = fmaxf(fmaf(A[j], xn, Bv[j]), 0.f);
        s = fmaf(w2[j * 9 + ky * 3 + kx], m1, s);
      }
    }
  }
  m[p] = 1.f / (1.f + expf(-s));
}

// ---------------- K_setup: block-invariant epilogue constants
__global__ __launch_bounds__(64) void k_setup(const float* __restrict__ w_in,
    const float* __restrict__ b_in, const float* __restrict__ out_b,
    const float* __restrict__ fc_w, const float* __restrict__ fc_b,
    float* __restrict__ fcA, float* __restrict__ bDg) {
  int d = threadIdx.x;
  float fa = 0.f, fb = 0.f;
  for (int c = 0; c < 64; c++) {
    float fw = fc_w[d * 64 + c];
    fa = fmaf(fw, w_in[c], fa);
    fb = fmaf(fw, b_in[c], fb);
  }
  fcA[d] = fa;
  bDg[d] = out_b[d] + fc_b[d] + fb;
}

// ---------------- K_cvtw: pre-convert the five 64x64 weight matrices to f16
__global__ __launch_bounds__(256) void k_cvtw(const float* __restrict__ a0,
    const float* __restrict__ a1, const float* __restrict__ a2,
    const float* __restrict__ a3, const float* __restrict__ a4,
    f16* __restrict__ dst) {
  int mtx = blockIdx.x;
  const float* s = (mtx == 0) ? a0 : (mtx == 1) ? a1 : (mtx == 2) ? a2 : (mtx == 3) ? a3 : a4;
  int t = threadIdx.x;
  for (int i = t; i < 4096; i += 256) dst[mtx * 4096 + i] = (f16)s[i];
}

// ---------------- K3a: init select state
__global__ __launch_bounds__(256) void k_init(unsigned* __restrict__ ghist,
    unsigned* __restrict__ prefix, int* __restrict__ rem) {
  int i = blockIdx.x * 256 + threadIdx.x;
  if (i < 8 * 2048) ghist[i] = 0u;
  if (i < 8) { prefix[i] = 0u; rem[i] = TOPK; }
}

// ---------------- K3b: grid-parallel histogram of one radix digit
template <int SHIFT, unsigned HIMASK, int BINS>
__global__ __launch_bounds__(256) void k_hist(const float* __restrict__ m,
    const unsigned* __restrict__ prefix, unsigned* __restrict__ ghist) {
  __shared__ unsigned hist[2048];
  int b = blockIdx.y, blk = blockIdx.x, t = threadIdx.x;
  for (int i = t; i < BINS; i += 256) hist[i] = 0u;
  __syncthreads();
  unsigned pfx = prefix[b];
  const float* mb = m + (size_t)b * NP + blk * (NP / HB);
#pragma unroll
  for (int it = 0; it < NP / HB / 256; it++) {
    unsigned bits = __float_as_uint(mb[it * 256 + t]);
    if ((bits & HIMASK) == pfx) atomicAdd(&hist[(bits >> SHIFT) & (BINS - 1)], 1u);
  }
  __syncthreads();
  unsigned* gh = ghist + b * 2048;
  for (int i = t; i < BINS; i += 256) {
    unsigned v = hist[i];
    if (v) atomicAdd(&gh[i], v);
  }
}

// ---------------- K3c: pick k-th bin via suffix scan; advance prefix/rem; zero ghist
template <int SHIFT, int BINS, int FINAL>
__global__ __launch_bounds__(256) void k_pick(unsigned* __restrict__ ghist,
    unsigned* __restrict__ prefix, int* __restrict__ rem,
    unsigned* __restrict__ selT, int* __restrict__ selNeed) {
  __shared__ unsigned s[256];
  int b = blockIdx.x, t = threadIdx.x;
  constexpr int PER = BINS / 256;
  unsigned* gh = ghist + b * 2048;
  unsigned local[PER];
  unsigned sum = 0;
#pragma unroll
  for (int j = 0; j < PER; j++) { local[j] = gh[t * PER + j]; sum += local[j]; }
#pragma unroll
  for (int j = 0; j < PER; j++) gh[t * PER + j] = 0u;
  s[t] = sum;
  int rm = rem[b];
  unsigned pfx = prefix[b];
  __syncthreads();
  for (int o = 1; o < 256; o <<= 1) {
    unsigned v = (t + o < 256) ? s[t + o] : 0u;
    __syncthreads();
    s[t] += v;
    __syncthreads();
  }
  unsigned nb = (t < 255) ? s[t + 1] : 0u;
  if (s[t] >= (unsigned)rm && nb < (unsigned)rm) {
    int acc = (int)nb;
#pragma unroll
    for (int j = PER - 1; j >= 0; j--) {
      acc += (int)local[j];
      if (acc >= rm) {
        unsigned bin = (unsigned)(t * PER + j);
        int need = rm - (acc - (int)local[j]);
        if (FINAL) {
          selT[b] = pfx | (bin << SHIFT);
          selNeed[b] = need;
        } else {
          prefix[b] = pfx | (bin << SHIFT);
          rem[b] = need;
        }
        break;
      }
    }
  }
}

// ---------------- K4a: per-chunk count of (bits == T)
__global__ __launch_bounds__(256) void k_cnteq(const float* __restrict__ m,
    const unsigned* __restrict__ selT, unsigned* __restrict__ cnt) {
  int b = blockIdx.y, ch = blockIdx.x, t = threadIdx.x;
  unsigned T = selT[b];
  unsigned bits = __float_as_uint(m[(size_t)b * NP + ch * 256 + t]);
  unsigned long long em = __ballot(bits == T);
  __shared__ unsigned wc[4];
  if ((t & 63) == 0) wc[t >> 6] = (unsigned)__popcll(em);
  __syncthreads();
  if (t == 0) cnt[b * CHUNKS + ch] = wc[0] + wc[1] + wc[2] + wc[3];
}

// ---------------- K4b: per-batch exclusive scan of chunk counts
__global__ __launch_bounds__(256) void k_scan(unsigned* __restrict__ cnt) {
  __shared__ unsigned s[256];
  int b = blockIdx.x, t = threadIdx.x;
  unsigned v = (t < CHUNKS) ? cnt[b * CHUNKS + t] : 0u;
  s[t] = v;
  __syncthreads();
  for (int o = 1; o < 256; o <<= 1) {
    unsigned u = (t >= o) ? s[t - o] : 0u;
    __syncthreads();
    s[t] += u;
    __syncthreads();
  }
  if (t < CHUNKS) cnt[b * CHUNKS + t] = s[t] - v;
}

// ---------------- K4c: stable mask write (ties by ascending index)
__global__ __launch_bounds__(256) void k_maskw(const float* __restrict__ m,
    const float* __restrict__ x,
    const unsigned* __restrict__ selT, const int* __restrict__ selNeed,
    const unsigned* __restrict__ cnt,
    f16* __restrict__ mx, f16* __restrict__ mk) {
  int b = blockIdx.y, ch = blockIdx.x, t = threadIdx.x;
  int lane = t & 63, wv = t >> 6;
  unsigned T = selT[b];
  int need = selNeed[b];
  size_t i = (size_t)b * NP + ch * 256 + t;
  unsigned bits = __float_as_uint(m[i]);
  bool gt = bits > T, eq = bits == T;
  unsigned long long em = __ballot(eq);
  __shared__ unsigned wc[4];
  if (lane == 0) wc[wv] = (unsigned)__popcll(em);
  __syncthreads();
  int base = (int)cnt[b * CHUNKS + ch];
  for (int w = 0; w < wv; w++) base += (int)wc[w];
  int rank = (int)__popcll(em & ((1ULL << lane) - 1ULL));
  bool sel = gt || (eq && (base + rank) < need);
  mk[i] = sel ? (f16)1.f : (f16)0.f;
  mx[i] = sel ? (f16)x[i] : (f16)0.f;
}

// ---------------- K5a: 4-row-grouped depthwise lvl0, weights in VGPRs, m unrolled
__global__ __launch_bounds__(256) void k_dw0(const float* __restrict__ dw_w,
    const float* __restrict__ w_in, const float* __restrict__ b_in,
    const f16* __restrict__ mx, const f16* __restrict__ mk,
    f16* __restrict__ outp) {
  constexpr int LOFF = 8, NLD = 3;
  int g = blockIdx.x * 256 + threadIdx.x;
  int w8 = g % 28;
  int rem = g / 28;
  int rowg = rem % 56, bc = rem / 56;
  int b = bc >> 6, c = bc & 63;
  int w0 = w8 * 8;
  int h0 = rowg * 4;
  const f16* mxb = mx + (size_t)b * NP;
  const f16* mkb = mk + (size_t)b * NP;
  float kw = w_in[64 + c], kb = b_in[64 + c];
  const float* wp = dw_w + c * 9;
  float wa[9], wb[9];
#pragma unroll
  for (int i = 0; i < 9; i++) {
    float wv = wp[i];
    wa[i] = wv * kw;
    wb[i] = wv * kb;
  }
  float acc[4][8] = {};
#pragma unroll
  for (int m = 0; m < 6; m++) {
    int him = h0 + m - 1;
    if ((unsigned)him >= (unsigned)HH) continue;
    float rx[NLD * 8], rk[NLD * 8];
    const f16* rpx = mxb + him * WW + (w0 - LOFF);
    const f16* rpk = mkb + him * WW + (w0 - LOFF);
#pragma unroll
    for (int s = 0; s < NLD; s++) {
      int ws_ = w0 - LOFF + s * 8;
      if ((unsigned)ws_ < (unsigned)WW) {
        f16x8 vx = *(const f16x8*)(rpx + s * 8);
        f16x8 vk = *(const f16x8*)(rpk + s * 8);
#pragma unroll
        for (int j = 0; j < 8; j++) { rx[s * 8 + j] = (float)vx[j]; rk[s * 8 + j] = (float)vk[j]; }
      } else {
#pragma unroll
        for (int j = 0; j < 8; j++) { rx[s * 8 + j] = 0.f; rk[s * 8 + j] = 0.f; }
      }
    }
#pragma unroll
    for (int j = 0; j < 4; j++) {
      constexpr unsigned K3 = 3u;
      int k = m - j;
      if ((unsigned)k >= K3) continue;
#pragma unroll
      for (int kx = 0; kx < 3; kx++) {
        float a_ = wa[k * 3 + kx], b_ = wb[k * 3 + kx];
#pragma unroll
        for (int p = 0; p < 8; p++) {
          int idx = p + LOFF + (kx - 1);
          acc[j][p] = fmaf(a_, rx[idx], fmaf(b_, rk[idx], acc[j][p]));
        }
      }
    }
  }
#pragma unroll
  for (int j = 0; j < 4; j++) {
    f16x8 o;
#pragma unroll
    for (int p = 0; p < 8; p++) o[p] = (f16)acc[j][p];
    *(f16x8*)(outp + (size_t)bc * NP + (h0 + j) * WW + w0) = o;
  }
}

// ---------------- K5b: 4-row-grouped depthwise lvl1/2, packed f32x2 FMA
// (legal because (kx-KSZ/2)*DIL is even for DIL in {2,4} -> aligned f32x2 pairs)
template <int KSZ, int DIL>
__global__ __launch_bounds__(256) void k_dw4(const float* __restrict__ dw_w,
    const f16* __restrict__ fin, f16* __restrict__ outp) {
  constexpr int PAD = (KSZ / 2) * DIL;
  constexpr int LOFF = (PAD + 7) & ~7;
  constexpr int NLD = (LOFF + 8 + PAD + 7) / 8;
  constexpr int NR = KSZ + 3;
  static_assert(DIL % 2 == 0, "packed pairs require even DIL");
  int g = blockIdx.x * 256 + threadIdx.x;
  int w8 = g % 28;
  int rem = g / 28;
  int rowg = rem % 56, bc = rem / 56;
  int w0 = w8 * 8;
  int res = rowg % DIL, grp = rowg / DIL;
  int h0 = res + DIL * 4 * grp;
  int c = bc & 63;
  const f16* fb = fin + (size_t)bc * NP;
  const float* wp = dw_w + c * KSZ * KSZ;
  float wr[KSZ * KSZ];
#pragma unroll
  for (int i = 0; i < KSZ * KSZ; i++) wr[i] = wp[i];
  f32x2 acc2[4][4] = {};
#pragma unroll
  for (int m = 0; m < NR; m++) {
    int him = h0 + (m - KSZ / 2) * DIL;
    if ((unsigned)him >= (unsigned)HH) continue;
    f32x2 r2[NLD * 4];
    const f16* rp = fb + him * WW + (w0 - LOFF);
#pragma unroll
    for (int s = 0; s < NLD; s++) {
      int ws_ = w0 - LOFF + s * 8;
      if ((unsigned)ws_ < (unsigned)WW) {
        f16x8 v = *(const f16x8*)(rp + s * 8);
#pragma unroll
        for (int pp = 0; pp < 4; pp++)
          r2[s * 4 + pp] = (f32x2){(float)v[2 * pp], (float)v[2 * pp + 1]};
      } else {
#pragma unroll
        for (int pp = 0; pp < 4; pp++) r2[s * 4 + pp] = (f32x2){0.f, 0.f};
      }
    }
#pragma unroll
    for (int j = 0; j < 4; j++) {
      int k = m - j;
      if (k < 0 || k >= KSZ) continue;
#pragma unroll
      for (int kx = 0; kx < KSZ; kx++) {
        float wv = wr[k * KSZ + kx];
        f32x2 wv2 = {wv, wv};
        constexpr int HALF = LOFF / 2;
#pragma unroll
        for (int pp = 0; pp < 4; pp++) {
          int idx = pp + HALF + (kx - KSZ / 2) * (DIL / 2);
          acc2[j][pp] = __builtin_elementwise_fma(wv2, r2[idx], acc2[j][pp]);
        }
      }
    }
  }
#pragma unroll
  for (int j = 0; j < 4; j++) {
    f16x8 o;
#pragma unroll
    for (int pp = 0; pp < 4; pp++) {
      o[2 * pp] = (f16)acc2[j][pp][0];
      o[2 * pp + 1] = (f16)acc2[j][pp][1];
    }
    *(f16x8*)(outp + (size_t)bc * NP + (h0 + DIL * j) * WW + w0) = o;
  }
}

// ---------------- K6: MFMA pointwise 64x64 + folded BN + relu (f16 weights)
__global__ __launch_bounds__(256) void k_pwm(const f16* __restrict__ inp,
    const f16* __restrict__ pwf, const float* __restrict__ pw_b,
    const float* __restrict__ g, const float* __restrict__ be,
    const float* __restrict__ mu, const float* __restrict__ var,
    f16* __restrict__ outp) {
  __shared__ f16 buf[128 * LDR];
  __shared__ float sc[64], sh[64];
  int t = threadIdx.x;
  if (t < 64) {
    float s = g[t] / sqrtf(var[t] + 1e-5f);
    sc[t] = s;
    sh[t] = (pw_b[t] - mu[t]) * s + be[t];
  }
  int b = blockIdx.y;
  int p0 = blockIdx.x * 128;
  const f16* src = inp + (size_t)b * 64 * NP + p0;
  f16x8 vv[4];
  int cis[4], pxs[4];
#pragma unroll
  for (int it = 0; it < 4; it++) {
    int cidx = it * 256 + t;
    cis[it] = cidx >> 4;
    pxs[it] = (cidx & 15) * 8;
    vv[it] = *(const f16x8*)(src + (size_t)cis[it] * NP + pxs[it]);
  }
#pragma unroll
  for (int it = 0; it < 4; it++) {
#pragma unroll
    for (int j = 0; j < 8; j++) buf[BIDX(pxs[it] + j, cis[it])] = vv[it][j];
  }
  __syncthreads();
  int ln = t & 63, wv = t >> 6;
  int r16 = ln & 15, g4 = ln >> 4;
  f16x8 af[4][2];
#pragma unroll
  for (int cb = 0; cb < 4; cb++)
#pragma unroll
    for (int ks = 0; ks < 2; ks++)
      af[cb][ks] = *(const f16x8*)(pwf + (cb * 16 + r16) * 64 + ks * 32 + g4 * 8);
#pragma unroll
  for (int pxb = 0; pxb < 2; pxb++) {
    int pl = wv * 32 + pxb * 16;
    f16x8 bf[2];
#pragma unroll
    for (int ks = 0; ks < 2; ks++)
      bf[ks] = *(const f16x8*)&buf[BIDX(pl + r16, ks * 32 + g4 * 8)];
    f32x4 acc[4];
#pragma unroll
    for (int cb = 0; cb < 4; cb++) acc[cb] = (f32x4){0.f, 0.f, 0.f, 0.f};
#pragma unroll
    for (int cb = 0; cb < 4; cb++)
#pragma unroll
      for (int ks = 0; ks < 2; ks++)
        acc[cb] = __builtin_amdgcn_mfma_f32_16x16x32_f16(af[cb][ks], bf[ks], acc[cb], 0, 0, 0);
    f16* dst = outp + (size_t)b * 64 * NP + p0 + pl + r16;
#pragma unroll
    for (int cb = 0; cb < 4; cb++)
#pragma unroll
      for (int j = 0; j < 4; j++) {
        int co = cb * 16 + g4 * 4 + j;
        float o = fmaf(acc[cb][j], sc[co], sh[co]);
        dst[(size_t)co * NP] = (f16)fmaxf(o, 0.f);
      }
  }
}

// ---------------- K7: K_global = mean over pixels of focal[2]
__global__ __launch_bounds__(256) void k_mean(const f16* __restrict__ F2,
                                              float* __restrict__ kg) {
  int bc = blockIdx.x;
  const f16* f = F2 + (size_t)bc * NP;
  float s = 0.f;
  for (int i = threadIdx.x; i < NP; i += 256) s += (float)f[i];
  __shared__ float r[256];
  r[threadIdx.x] = s;
  __syncthreads();
  for (int o = 128; o > 0; o >>= 1) {
    if (threadIdx.x < o) r[threadIdx.x] += r[threadIdx.x + o];
    __syncthreads();
  }
  if (threadIdx.x == 0) kg[bc] = r[0] * (1.f / NP);
}

// ---------------- K8: fused K_final -> V -> QV -> out (f16 weights)
__global__ __launch_bounds__(256) void k_final(const float* __restrict__ x,
    const float* __restrict__ w_in, const float* __restrict__ b_in,
    const f16* __restrict__ F0, const f16* __restrict__ F1, const f16* __restrict__ F2,
    const float* __restrict__ kg, const float* __restrict__ fcA,
    const float* __restrict__ bDg,
    const f16* __restrict__ vwf, const float* __restrict__ v_b,
    const f16* __restrict__ owf,
    float* __restrict__ outp) {
  __shared__ f16 buf[128 * LDR];
  __shared__ float gvs[128 * 4];  // row r = gv for px = IROT(r)
  __shared__ float xs[128];
  __shared__ float kgs[64], qwS[64], qbS[64], vbS[64], bD[64], fcAS[64];
  int t = threadIdx.x;
  int b = blockIdx.y;
  int p0 = blockIdx.x * 128;
  if (t < 64) {
    kgs[t] = kg[b * 64 + t];
    qwS[t] = w_in[t];
    qbS[t] = b_in[t];
    vbS[t] = v_b[t];
    fcAS[t] = fcA[t];
    bD[t] = bDg[t];
  }
  if (t < 128) {
    int px = ((t & 15) << 3) | (t >> 4);  // IROT(t)
    float xv = x[(size_t)b * NP + p0 + px];
    xs[px] = xv;
    float gv[4], mxv = -1e30f;
#pragma unroll
    for (int j = 0; j < 4; j++) {
      gv[j] = fmaf(xv, w_in[128 + j], b_in[128 + j]);
      mxv = fmaxf(mxv, gv[j]);
    }
    float se = 0.f;
#pragma unroll
    for (int j = 0; j < 4; j++) { gv[j] = expf(gv[j] - mxv); se += gv[j]; }
    float inv = 1.f / se;
    f32x4 g4v;
#pragma unroll
    for (int j = 0; j < 4; j++) g4v[j] = gv[j] * inv;
    *(f32x4*)&gvs[t * 4] = g4v;
  }
  const f16* f0 = F0 + (size_t)b * 64 * NP + p0;
  const f16* f1 = F1 + (size_t)b * 64 * NP + p0;
  const f16* f2 = F2 + (size_t)b * 64 * NP + p0;
  f16x8 s0[4], s1[4], s2[4];
  int cis[4], pxs[4];
#pragma unroll
  for (int it = 0; it < 4; it++) {
    int cidx = it * 256 + t;
    cis[it] = cidx >> 4;
    pxs[it] = (cidx & 15) * 8;
    size_t o = (size_t)cis[it] * NP + pxs[it];
    s0[it] = *(const f16x8*)(f0 + o);
    s1[it] = *(const f16x8*)(f1 + o);
    s2[it] = *(const f16x8*)(f2 + o);
  }
  int ln = t & 63, wv = t >> 6;
  int r16 = ln & 15, g4 = ln >> 4;
  f16x8 afV[4][2];
#pragma unroll
  for (int cb = 0; cb < 4; cb++)
#pragma unroll
    for (int ks = 0; ks < 2; ks++)
      afV[cb][ks] = *(const f16x8*)(vwf + (cb * 16 + r16) * 64 + ks * 32 + g4 * 8);
  __syncthreads();
#pragma unroll
  for (int it = 0; it < 4; it++) {
    int ci = cis[it], px8 = pxs[it];
    float kgc = kgs[ci];
#pragma unroll
    for (int j = 0; j < 8; j++) {
      int px = px8 + j;
      f32x4 gv = *(const f32x4*)&gvs[(((px & 7) << 4) | (px >> 3)) * 4];
      float kf = gv[0] * (float)s0[it][j] + gv[1] * (float)s1[it][j] +
                 gv[2] * (float)s2[it][j] + gv[3] * kgc;
      buf[BIDX(px, ci)] = (f16)kf;
    }
  }
  __syncthreads();
  {
#pragma unroll
    for (int pxb = 0; pxb < 2; pxb++) {
      int pl = wv * 32 + pxb * 16;
      f16x8 bf[2];
#pragma unroll
      for (int ks = 0; ks < 2; ks++)
        bf[ks] = *(const f16x8*)&buf[BIDX(pl + r16, ks * 32 + g4 * 8)];
      f32x4 acc[4];
#pragma unroll
      for (int cb = 0; cb < 4; cb++) acc[cb] = (f32x4){0.f, 0.f, 0.f, 0.f};
#pragma unroll
      for (int cb = 0; cb < 4; cb++)
#pragma unroll
        for (int ks = 0; ks < 2; ks++)
          acc[cb] = __builtin_amdgcn_mfma_f32_16x16x32_f16(afV[cb][ks], bf[ks], acc[cb], 0, 0, 0);
      int px = pl + r16;
      float xv = xs[px];
#pragma unroll
      for (int cb = 0; cb < 4; cb++) {
        f16x4 q4;
#pragma unroll
        for (int j = 0; j < 4; j++) {
          int co = cb * 16 + g4 * 4 + j;
          float V = acc[cb][j] + vbS[co];
          float q = fmaf(xv, qwS[co], qbS[co]);
          q4[j] = (f16)(q * V);
        }
        *(f16x4*)&buf[BIDX(px, cb * 16 + g4 * 4)] = q4;
      }
    }
  }
  f16x8 afO[4][2];
#pragma unroll
  for (int cb = 0; cb < 4; cb++)
#pragma unroll
    for (int ks = 0; ks < 2; ks++)
      afO[cb][ks] = *(const f16x8*)(owf + (cb * 16 + r16) * 64 + ks * 32 + g4 * 8);
  __syncthreads();
  {
#pragma unroll
    for (int pxb = 0; pxb < 2; pxb++) {
      int pl = wv * 32 + pxb * 16;
      f16x8 bf[2];
#pragma unroll
      for (int ks = 0; ks < 2; ks++)
        bf[ks] = *(const f16x8*)&buf[BIDX(pl + r16, ks * 32 + g4 * 8)];
      f32x4 acc[4];
#pragma unroll
      for (int cb = 0; cb < 4; cb++) acc[cb] = (f32x4){0.f, 0.f, 0.f, 0.f};
#pragma unroll
      for (int cb = 0; cb < 4; cb++)
#pragma unroll
        for (int ks = 0; ks < 2; ks++)
          acc[cb] = __builtin_amdgcn_mfma_f32_16x16x32_f16(afO[cb][ks], bf[ks], acc[cb], 0, 0, 0);
      int px = pl + r16;
      float xv = xs[px];
      float* dst = outp + (size_t)b * 64 * NP + p0 + px;
#pragma unroll
      for (int cb = 0; cb < 4; cb++)
#pragma unroll
        for (int j = 0; j < 4; j++) {
          int d = cb * 16 + g4 * 4 + j;
          dst[(size_t)d * NP] = acc[cb][j] + bD[d] + xv * fcAS[d];
        }
    }
  }
}

extern "C" void kernel_launch(void* const* d_in, const int* in_sizes, int n_in,
                              void* d_out, int out_size, void* d_ws, size_t ws_size,
                              hipStream_t stream) {
  const float* x = (const float*)d_in[0];
  const float* w_in = (const float*)d_in[1];
  const float* b_in = (const float*)d_in[2];
  const float* dw_w[3] = {(const float*)d_in[3], (const float*)d_in[10], (const float*)d_in[17]};
  const float* pw_w[3] = {(const float*)d_in[4], (const float*)d_in[11], (const float*)d_in[18]};
  const float* pw_b[3] = {(const float*)d_in[5], (const float*)d_in[12], (const float*)d_in[19]};
  const float* bng[3] = {(const float*)d_in[6], (const float*)d_in[13], (const float*)d_in[20]};
  const float* bnb[3] = {(const float*)d_in[7], (const float*)d_in[14], (const float*)d_in[21]};
  const float* bnm[3] = {(const float*)d_in[8], (const float*)d_in[15], (const float*)d_in[22]};
  const float* bnv[3] = {(const float*)d_in[9], (const float*)d_in[16], (const float*)d_in[23]};
  const float* imp1_w = (const float*)d_in[24];
  const float* imp1_b = (const float*)d_in[25];
  const float* imp2_w = (const float*)d_in[26];
  const float* imp2_b = (const float*)d_in[27];
  const float* v_w = (const float*)d_in[28];
  const float* v_b = (const float*)d_in[29];
  const float* out_w = (const float*)d_in[30];
  const float* out_b = (const float*)d_in[31];
  const float* fc_w = (const float*)d_in[32];
  const float* fc_b = (const float*)d_in[33];

  char* ws = (char*)d_ws;
  size_t off = 0;
  auto alloc = [&](size_t sz) {
    size_t o = off;
    off = (off + sz + 255) & ~(size_t)255;
    return o;
  };
  float* mbuf = (float*)(ws + alloc((size_t)BB * NP * 4));
  unsigned* ghist = (unsigned*)(ws + alloc((size_t)BB * 2048 * 4));
  unsigned* prefix = (unsigned*)(ws + alloc(8 * 4));
  int* remv = (int*)(ws + alloc(8 * 4));
  unsigned* selT = (unsigned*)(ws + alloc(8 * 4));
  int* selNeed = (int*)(ws + alloc(8 * 4));
  unsigned* cntbuf = (unsigned*)(ws + alloc((size_t)BB * CHUNKS * 4));
  float* fcA = (float*)(ws + alloc(64 * 4));
  float* bDg = (float*)(ws + alloc(64 * 4));
  f16* wf = (f16*)(ws + alloc((size_t)5 * 4096 * 2));  // pw0,pw1,pw2,v_w,out_w (f16)
  f16* mx = (f16*)(ws + alloc((size_t)BB * NP * 2));
  f16* mk = (f16*)(ws + alloc((size_t)BB * NP * 2));
  f16* tmp = (f16*)(ws + alloc((size_t)BB * 64 * NP * 2));
  f16* F0 = (f16*)(ws + alloc((size_t)BB * 64 * NP * 2));
  f16* F1 = (f16*)(ws + alloc((size_t)BB * 64 * NP * 2));
  f16* F2 = (f16*)(ws + alloc((size_t)BB * 64 * NP * 2));
  float* kg = (float*)(ws + alloc(512 * 4));

  const int PIX_BLKS = (BB * NP) / 256;              // 1568
  const int DW4_BLKS = (BB * 64 * 56 * 28) / 256;    // 3136
  dim3 tile_grid(NP / 128, BB);                      // 392 x 8
  dim3 chunk_grid(CHUNKS, BB);                       // 196 x 8
  dim3 hist_grid(HB, BB);                            // 28 x 8

  k_m<<<PIX_BLKS, 256, 0, stream>>>(x, w_in, b_in, imp1_w, imp1_b, imp2_w, imp2_b, mbuf);
  k_init<<<64, 256, 0, stream>>>(ghist, prefix, remv);
  k_setup<<<1, 64, 0, stream>>>(w_in, b_in, out_b, fc_w, fc_b, fcA, bDg);
  k_cvtw<<<5, 256, 0, stream>>>(pw_w[0], pw_w[1], pw_w[2], v_w, out_w, wf);
  // 3-pass radix select: 11 + 11 + 10 bits
  k_hist<21, 0u, 2048><<<hist_grid, 256, 0, stream>>>(mbuf, prefix, ghist);
  k_pick<21, 2048, 0><<<BB, 256, 0, stream>>>(ghist, prefix, remv, selT, selNeed);
  k_hist<10, 0xFFE00000u, 2048><<<hist_grid, 256, 0, stream>>>(mbuf, prefix, ghist);
  k_pick<10, 2048, 0><<<BB, 256, 0, stream>>>(ghist, prefix, remv, selT, selNeed);
  k_hist<0, 0xFFFFFC00u, 1024><<<hist_grid, 256, 0, stream>>>(mbuf, prefix, ghist);
  k_pick<0, 1024, 1><<<BB, 256, 0, stream>>>(ghist, prefix, remv, selT, selNeed);

  k_cnteq<<<chunk_grid, 256, 0, stream>>>(mbuf, selT, cntbuf);
  k_scan<<<BB, 256, 0, stream>>>(cntbuf);
  k_maskw<<<chunk_grid, 256, 0, stream>>>(mbuf, x, selT, selNeed, cntbuf, mx, mk);

  // level 0
  k_dw0<<<DW4_BLKS, 256, 0, stream>>>(dw_w[0], w_in, b_in, mx, mk, tmp);
  k_pwm<<<tile_grid, 256, 0, stream>>>(tmp, wf + 0 * 4096, pw_b[0], bng[0], bnb[0], bnm[0], bnv[0], F0);
  // level 1
  k_dw4<5, 2><<<DW4_BLKS, 256, 0, stream>>>(dw_w[1], F0, tmp);
  k_pwm<<<tile_grid, 256, 0, stream>>>(tmp, wf + 1 * 4096, pw_b[1], bng[1], bnb[1], bnm[1], bnv[1], F1);
  // level 2
  k_dw4<7, 4><<<DW4_BLKS, 256, 0, stream>>>(dw_w[2], F1, tmp);
  k_pwm<<<tile_grid, 256, 0, stream>>>(tmp, wf + 2 * 4096, pw_b[2], bng[2], bnb[2], bnm[2], bnv[2], F2);

  k_mean<<<512, 256, 0, stream>>>(F2, kg);
  k_final<<<tile_grid, 256, 0, stream>>>(x, w_in, b_in, F0, F1, F2, kg, fcA, bDg,
                                         wf + 3 * 4096, v_b, wf + 4 * 4096, (float*)d_out);
}